// Round 1
// baseline (1271.866 us; speedup 1.0000x reference)
//
#include <hip/hip_runtime.h>
#include <hip/hip_bf16.h>
#include <hip/hip_fp16.h>

#define NB 8192
#define D_IN 3200
#define D_H 128
#define NE 5
#define TOK 16

typedef _Float16 f16x8 __attribute__((ext_vector_type(8)));
typedef float f32x4 __attribute__((ext_vector_type(4)));

// ---------------- kernel 0: e1_w [5][3200][128] f32 -> f16 transposed [5][128][3200]
__global__ __launch_bounds__(256) void k_wconv(const float* __restrict__ e1w,
                                               _Float16* __restrict__ wT) {
    __shared__ float tile[64][65];
    int e = blockIdx.x;
    int k0 = blockIdx.y * 64;
    int n0 = blockIdx.z * 64;
    const float* src = e1w + (size_t)e * D_IN * D_H;
    _Float16* dst = wT + (size_t)e * D_H * D_IN;
    int t = threadIdx.x;
    for (int i = 0; i < 16; ++i) {
        int idx = t + i * 256;
        int kr = idx >> 6, nc = idx & 63;
        tile[kr][nc] = src[(size_t)(k0 + kr) * D_H + n0 + nc];
    }
    __syncthreads();
    for (int i = 0; i < 16; ++i) {
        int idx = t + i * 256;
        int nr = idx >> 6, kc = idx & 63;
        dst[(size_t)(n0 + nr) * D_IN + k0 + kc] = (_Float16)tile[kc][nr];
    }
}

// ---------------- kernel 1: conv1+relu -> pool -> conv2+relu -> h (f16) + gate top-3
__global__ __launch_bounds__(256) void k_feat(
    const float* __restrict__ x, const float* __restrict__ c1w, const float* __restrict__ c1b,
    const float* __restrict__ c2w, const float* __restrict__ c2b,
    const float* __restrict__ gw, const float* __restrict__ gb,
    _Float16* __restrict__ h16, float* __restrict__ wfull)
{
    __shared__ float xs[784];
    __shared__ float c1ws[400];
    __shared__ float c1o[9216];
    __shared__ float pools[2304];
    __shared__ float hbuf[3200];
    __shared__ float red[4][8];
    int b = blockIdx.x;
    int t = threadIdx.x;
    for (int i = t; i < 784; i += 256) xs[i] = x[(size_t)b * 784 + i];
    for (int i = t; i < 400; i += 256) c1ws[i] = c1w[i];
    __syncthreads();
    // conv1 5x5 valid + relu: [16,24,24]
    for (int idx = t; idx < 9216; idx += 256) {
        int co = idx / 576;
        int rem = idx - co * 576;
        int r = rem / 24;
        int j = rem - r * 24;
        float s = c1b[co];
        const float* wp = &c1ws[co * 25];
        #pragma unroll
        for (int u = 0; u < 5; ++u)
            #pragma unroll
            for (int v = 0; v < 5; ++v)
                s += xs[(r + u) * 28 + (j + v)] * wp[u * 5 + v];
        c1o[idx] = fmaxf(s, 0.f);
    }
    __syncthreads();
    // 2x2 maxpool: [16,12,12]
    for (int idx = t; idx < 2304; idx += 256) {
        int c = idx / 144;
        int rem = idx - c * 144;
        int r = rem / 12;
        int j = rem - r * 12;
        const float* p = &c1o[c * 576 + (2 * r) * 24 + 2 * j];
        pools[idx] = fmaxf(fmaxf(p[0], p[1]), fmaxf(p[24], p[25]));
    }
    __syncthreads();
    // conv2 3x3 valid + relu: [32,10,10] -> flatten 3200
    for (int idx = t; idx < 3200; idx += 256) {
        int co = idx / 100;
        int rem = idx - co * 100;
        int r = rem / 10;
        int j = rem - r * 10;
        float s = c2b[co];
        #pragma unroll
        for (int ci = 0; ci < 16; ++ci) {
            const float* pp = &pools[ci * 144 + r * 12 + j];
            const float* wp = &c2w[(co * 16 + ci) * 9];
            s += pp[0] * wp[0] + pp[1] * wp[1] + pp[2] * wp[2]
               + pp[12] * wp[3] + pp[13] * wp[4] + pp[14] * wp[5]
               + pp[24] * wp[6] + pp[25] * wp[7] + pp[26] * wp[8];
        }
        s = fmaxf(s, 0.f);
        hbuf[idx] = s;
        h16[(size_t)b * D_IN + idx] = (_Float16)s;
    }
    __syncthreads();
    // gate: logits = h @ gw + gb, softmax, top-3 renormalized
    float part[5] = {0, 0, 0, 0, 0};
    for (int k = t; k < 3200; k += 256) {
        float hv = hbuf[k];
        const float* g = &gw[k * 5];
        part[0] += hv * g[0]; part[1] += hv * g[1]; part[2] += hv * g[2];
        part[3] += hv * g[3]; part[4] += hv * g[4];
    }
    int lane = t & 63, wv = t >> 6;
    #pragma unroll
    for (int e = 0; e < 5; ++e) {
        float v = part[e];
        for (int off = 32; off > 0; off >>= 1) v += __shfl_down(v, off, 64);
        if (lane == 0) red[wv][e] = v;
    }
    __syncthreads();
    if (t == 0) {
        float lg[5], p[5];
        float mx = -1e30f;
        for (int e = 0; e < 5; ++e) {
            lg[e] = red[0][e] + red[1][e] + red[2][e] + red[3][e] + gb[e];
            mx = fmaxf(mx, lg[e]);
        }
        float sum = 0.f;
        for (int e = 0; e < 5; ++e) { p[e] = expf(lg[e] - mx); sum += p[e]; }
        for (int e = 0; e < 5; ++e) p[e] /= sum;
        bool used[5] = {false, false, false, false, false};
        float out5[5] = {0, 0, 0, 0, 0};
        int ti[3]; float tv[3]; float tsum = 0.f;
        for (int jj = 0; jj < 3; ++jj) {
            int best = 0; float bv = -1.f;
            for (int e = 0; e < 5; ++e)
                if (!used[e] && p[e] > bv) { bv = p[e]; best = e; }
            used[best] = true; ti[jj] = best; tv[jj] = bv; tsum += bv;
        }
        for (int jj = 0; jj < 3; ++jj) out5[ti[jj]] = tv[jj] / tsum;
        for (int e = 0; e < 5; ++e) wfull[b * 5 + e] = out5[e];
    }
}

// ---------------- kernel 2: h1[e,b,n] = tanh(h @ e1_w[e] + b1[e])  (f16 MFMA GEMM)
// block tile 64(M) x 128(N), BK=32, 4 waves each 32x64
__global__ __launch_bounds__(256) void k_e1(
    const _Float16* __restrict__ h16, const _Float16* __restrict__ wT,
    const float* __restrict__ e1b, float* __restrict__ h1)
{
    __shared__ __align__(16) _Float16 As[64 * 32];
    __shared__ __align__(16) _Float16 Bs[128 * 32];
    int mt = blockIdx.x, e = blockIdx.y;
    int m0 = mt * 64;
    int t = threadIdx.x;
    int lane = t & 63, wv = t >> 6;
    int waveM = wv >> 1, waveN = wv & 1;
    int quad = lane >> 4, l16 = lane & 15;
    const _Float16* wbase = wT + (size_t)e * D_H * D_IN;
    f32x4 acc[2][4];
    #pragma unroll
    for (int i = 0; i < 2; ++i)
        #pragma unroll
        for (int j = 0; j < 4; ++j) acc[i][j] = (f32x4){0.f, 0.f, 0.f, 0.f};
    int arow = t >> 2, acol = (t & 3) * 8;   // 64 rows x 32 cols, 16B per thread
    for (int k0 = 0; k0 < D_IN; k0 += 32) {
        *(uint4*)(&As[arow * 32 + acol]) =
            *(const uint4*)(&h16[(size_t)(m0 + arow) * D_IN + k0 + acol]);
        *(uint4*)(&Bs[arow * 32 + acol]) =
            *(const uint4*)(&wbase[(size_t)arow * D_IN + k0 + acol]);
        *(uint4*)(&Bs[(arow + 64) * 32 + acol]) =
            *(const uint4*)(&wbase[(size_t)(arow + 64) * D_IN + k0 + acol]);
        __syncthreads();
        f16x8 a[2], bfr[4];
        #pragma unroll
        for (int ms = 0; ms < 2; ++ms)
            a[ms] = *(const f16x8*)(&As[(waveM * 32 + ms * 16 + l16) * 32 + quad * 8]);
        #pragma unroll
        for (int ns = 0; ns < 4; ++ns)
            bfr[ns] = *(const f16x8*)(&Bs[(waveN * 64 + ns * 16 + l16) * 32 + quad * 8]);
        #pragma unroll
        for (int ms = 0; ms < 2; ++ms)
            #pragma unroll
            for (int ns = 0; ns < 4; ++ns)
                acc[ms][ns] = __builtin_amdgcn_mfma_f32_16x16x32_f16(a[ms], bfr[ns], acc[ms][ns], 0, 0, 0);
        __syncthreads();
    }
    // epilogue: D row = quad*4 + reg, col = l16 (within 16x16 tile)
    #pragma unroll
    for (int ms = 0; ms < 2; ++ms) {
        int mbase = m0 + waveM * 32 + ms * 16 + quad * 4;
        #pragma unroll
        for (int ns = 0; ns < 4; ++ns) {
            int n = waveN * 64 + ns * 16 + l16;
            float bias = e1b[e * D_H + n];
            #pragma unroll
            for (int r = 0; r < 4; ++r) {
                int m = mbase + r;
                h1[((size_t)e * NB + m) * D_H + n] = tanhf(acc[ms][ns][r] + bias);
            }
        }
    }
}

// ---------------- kernel 3: h2 = tanh(h1 @ e2_w + b2); moe = sum_e w*h2; head softmax
__global__ __launch_bounds__(128) void k_moe(
    const float* __restrict__ h1, const float* __restrict__ wfull,
    const float* __restrict__ e2w, const float* __restrict__ e2b,
    const float* __restrict__ smw, const float* __restrict__ smb,
    float* __restrict__ out)
{
    __shared__ float wlds[64][128];   // half of e2_w[e], K-split
    __shared__ float h1s[TOK][128];
    __shared__ float wf[TOK][5];
    __shared__ float lg[TOK][10];
    int b0 = blockIdx.x * TOK;
    int n = threadIdx.x;   // 0..127
    for (int i = n; i < TOK * 5; i += 128)
        wf[i / 5][i % 5] = wfull[(size_t)(b0 + i / 5) * 5 + (i % 5)];
    float moe[TOK];
    #pragma unroll
    for (int tt = 0; tt < TOK; ++tt) moe[tt] = 0.f;
    __syncthreads();
    for (int e = 0; e < NE; ++e) {
        bool any = false;
        for (int tt = 0; tt < TOK; ++tt) any = any || (wf[tt][e] > 0.f);
        if (!any) continue;                      // uniform across block
        float pre[TOK];
        float bias = e2b[e * D_H + n];
        #pragma unroll
        for (int tt = 0; tt < TOK; ++tt) pre[tt] = bias;
        __syncthreads();                          // prior users of h1s/wlds done
        for (int tt = 0; tt < TOK; ++tt)
            h1s[tt][n] = h1[((size_t)e * NB + b0 + tt) * D_H + n];
        for (int kh = 0; kh < 2; ++kh) {
            if (kh) __syncthreads();              // compute of kh=0 done before reload
            for (int k = 0; k < 64; ++k)
                wlds[k][n] = e2w[(size_t)e * D_H * D_H + (kh * 64 + k) * D_H + n];
            __syncthreads();
            for (int tt = 0; tt < TOK; ++tt) {
                if (!(wf[tt][e] > 0.f)) continue; // uniform (wf same for all threads)
                #pragma unroll 8
                for (int k = 0; k < 64; ++k)
                    pre[tt] += h1s[tt][kh * 64 + k] * wlds[k][n];
            }
        }
        #pragma unroll
        for (int tt = 0; tt < TOK; ++tt)
            if (wf[tt][e] > 0.f) moe[tt] += wf[tt][e] * tanhf(pre[tt]);
    }
    // head: logits = moe @ smw + smb, softmax over 10
    __syncthreads();
    float* moes = &wlds[0][0];                    // reuse LDS
    for (int tt = 0; tt < TOK; ++tt) moes[tt * 128 + n] = moe[tt];
    __syncthreads();
    for (int i = n; i < TOK * 10; i += 128) {
        int tt = i / 10, c = i - (i / 10) * 10;
        float s = smb[c];
        for (int kk = 0; kk < 128; ++kk) s += moes[tt * 128 + kk] * smw[kk * 10 + c];
        lg[tt][c] = s;
    }
    __syncthreads();
    if (n < TOK) {
        float mx = -1e30f;
        for (int c = 0; c < 10; ++c) mx = fmaxf(mx, lg[n][c]);
        float s = 0.f, ex[10];
        for (int c = 0; c < 10; ++c) { ex[c] = expf(lg[n][c] - mx); s += ex[c]; }
        float inv = 1.f / s;
        for (int c = 0; c < 10; ++c) out[(size_t)(b0 + n) * 10 + c] = ex[c] * inv;
    }
}

extern "C" void kernel_launch(void* const* d_in, const int* in_sizes, int n_in,
                              void* d_out, int out_size, void* d_ws, size_t ws_size,
                              hipStream_t stream)
{
    const float* x   = (const float*)d_in[0];
    const float* c1w = (const float*)d_in[1];
    const float* c1b = (const float*)d_in[2];
    const float* c2w = (const float*)d_in[3];
    const float* c2b = (const float*)d_in[4];
    const float* gw  = (const float*)d_in[5];
    const float* gb  = (const float*)d_in[6];
    const float* e1w = (const float*)d_in[7];
    const float* e1b = (const float*)d_in[8];
    const float* e2w = (const float*)d_in[9];
    const float* e2b = (const float*)d_in[10];
    const float* smw = (const float*)d_in[11];
    const float* smb = (const float*)d_in[12];
    float* out = (float*)d_out;

    // workspace carve (≈78 MB total)
    char* ws = (char*)d_ws;
    size_t off = 0;
    auto alloc = [&](size_t bytes) {
        void* p = ws + off;
        off += (bytes + 255) & ~(size_t)255;
        return p;
    };
    _Float16* h16 = (_Float16*)alloc((size_t)NB * D_IN * 2);          // 52.4 MB
    _Float16* wT  = (_Float16*)alloc((size_t)NE * D_H * D_IN * 2);    // 4.1 MB
    float* wfull  = (float*)alloc((size_t)NB * NE * 4);               // 0.16 MB
    float* h1     = (float*)alloc((size_t)NE * NB * D_H * 4);         // 21 MB

    k_wconv<<<dim3(NE, D_IN / 64, D_H / 64), 256, 0, stream>>>(e1w, wT);
    k_feat<<<dim3(NB), 256, 0, stream>>>(x, c1w, c1b, c2w, c2b, gw, gb, h16, wfull);
    k_e1<<<dim3(NB / 64, NE), 256, 0, stream>>>(h16, wT, e1b, h1);
    k_moe<<<dim3(NB / TOK), 128, 0, stream>>>(h1, wfull, e2w, e2b, smw, smb, out);
}

// Round 2
// 466.461 us; speedup vs baseline: 2.7266x; 2.7266x over previous
//
#include <hip/hip_runtime.h>
#include <hip/hip_bf16.h>
#include <hip/hip_fp16.h>

#define NB 8192
#define D_IN 3200
#define D_H 128
#define NE 5
#define TOK 16

typedef _Float16 f16x8 __attribute__((ext_vector_type(8)));
typedef float f32x4 __attribute__((ext_vector_type(4)));

// ---------------- kernel 0: e1_w [5][3200][128] f32 -> f16 transposed [5][128][3200]
__global__ __launch_bounds__(256) void k_wconv(const float* __restrict__ e1w,
                                               _Float16* __restrict__ wT) {
    __shared__ float tile[64][65];
    int e = blockIdx.x;
    int k0 = blockIdx.y * 64;
    int n0 = blockIdx.z * 64;
    const float* src = e1w + (size_t)e * D_IN * D_H;
    _Float16* dst = wT + (size_t)e * D_H * D_IN;
    int t = threadIdx.x;
    for (int i = 0; i < 16; ++i) {
        int idx = t + i * 256;
        int kr = idx >> 6, nc = idx & 63;
        tile[kr][nc] = src[(size_t)(k0 + kr) * D_H + n0 + nc];
    }
    __syncthreads();
    for (int i = 0; i < 16; ++i) {
        int idx = t + i * 256;
        int nr = idx >> 6, kc = idx & 63;
        dst[(size_t)(n0 + nr) * D_IN + k0 + kc] = (_Float16)tile[kc][nr];
    }
}

// ---------------- kernel 1: conv1+pool fused -> conv2 -> h (f16) + gate top-3
// Register-blocked: conv1 thread = (channel, 3x3 pooled tile); conv2 thread =
// (4-co group, 2x2 spatial block). LDS ~50KB -> 3 blocks/CU.
__global__ __launch_bounds__(256) void k_feat(
    const float* __restrict__ x, const float* __restrict__ c1w, const float* __restrict__ c1b,
    const float* __restrict__ c2w, const float* __restrict__ c2b,
    const float* __restrict__ gw, const float* __restrict__ gb,
    _Float16* __restrict__ h16, float* __restrict__ wfull)
{
    __shared__ __align__(16) float xs[784];          // 3136 B
    __shared__ __align__(16) float c1wsP[16 * 28];   // 1792 B (25 padded to 28)
    __shared__ __align__(16) float w2s[16 * 32 * 12];// 24576 B  [ci][co][12] (9 padded)
    __shared__ __align__(16) float pools[16 * 144];  // 9216 B   [ci][12][12]
    __shared__ __align__(16) float hbuf[3200];       // 12800 B
    __shared__ float red[4][8];
    int b = blockIdx.x;
    int t = threadIdx.x;

    // ---- stage inputs/weights
    for (int i = t; i < 784; i += 256) xs[i] = x[(size_t)b * 784 + i];
    for (int i = t; i < 400; i += 256) {
        int c = i / 25, q = i - c * 25;
        c1wsP[c * 28 + q] = c1w[i];
    }
    for (int i = t; i < 4608; i += 256) {
        int co = i / 144, rem = i - co * 144;
        int ci = rem / 9, q = rem - ci * 9;
        w2s[ci * 384 + co * 12 + q] = c2w[i];
    }
    __syncthreads();

    // ---- conv1 (5x5 valid, relu) fused with 2x2 maxpool -> pools[16][12][12]
    {
        int c = t >> 4;            // channel 0..15
        int tile = t & 15;
        int tr = tile >> 2, tc = tile & 3;   // 3x3 pooled tile origin (3tr, 3tc)
        float w1r[25];
        #pragma unroll
        for (int q = 0; q < 6; ++q) {
            float4 v4 = *(const float4*)&c1wsP[c * 28 + q * 4];
            w1r[q * 4 + 0] = v4.x; w1r[q * 4 + 1] = v4.y;
            w1r[q * 4 + 2] = v4.z; w1r[q * 4 + 3] = v4.w;
        }
        w1r[24] = c1wsP[c * 28 + 24];
        float bias1 = c1b[c];
        float win[5][10];
        float pacc[3][3];
        #pragma unroll
        for (int i = 0; i < 3; ++i)
            #pragma unroll
            for (int j = 0; j < 3; ++j) pacc[i][j] = 0.f;
        int r0 = 6 * tr, col0 = 6 * tc;
        #pragma unroll
        for (int cr = 0; cr < 6; ++cr) {
            if (cr == 0) {
                #pragma unroll
                for (int rr = 0; rr < 5; ++rr)
                    #pragma unroll
                    for (int m = 0; m < 5; ++m) {
                        float2 v = *(const float2*)&xs[(r0 + rr) * 28 + col0 + 2 * m];
                        win[rr][2 * m] = v.x; win[rr][2 * m + 1] = v.y;
                    }
            } else {
                int dstr = (cr + 4) % 5;
                #pragma unroll
                for (int m = 0; m < 5; ++m) {
                    float2 v = *(const float2*)&xs[(r0 + cr + 4) * 28 + col0 + 2 * m];
                    win[dstr][2 * m] = v.x; win[dstr][2 * m + 1] = v.y;
                }
            }
            #pragma unroll
            for (int oc = 0; oc < 6; ++oc) {
                float s = bias1;
                #pragma unroll
                for (int u = 0; u < 5; ++u)
                    #pragma unroll
                    for (int v = 0; v < 5; ++v)
                        s += win[(cr + u) % 5][oc + v] * w1r[u * 5 + v];
                s = fmaxf(s, 0.f);
                pacc[cr >> 1][oc >> 1] = fmaxf(pacc[cr >> 1][oc >> 1], s);
            }
        }
        #pragma unroll
        for (int i = 0; i < 3; ++i)
            #pragma unroll
            for (int j = 0; j < 3; ++j)
                pools[c * 144 + (3 * tr + i) * 12 + (3 * tc + j)] = pacc[i][j];
    }
    __syncthreads();

    // ---- conv2 (3x3 valid over 16 ci, relu) -> hbuf[3200]
    {
        int cog = t >> 5;          // 0..7 -> co = 4*cog..4*cog+3
        int sb = t & 31;           // spatial 2x2 block, 25 active
        if (sb < 25) {
            int sr = sb / 5, sc = sb - (sb / 5) * 5;   // block origin (2sr, 2sc)
            float acc2[4][4];
            #pragma unroll
            for (int co4 = 0; co4 < 4; ++co4) {
                float bb = c2b[cog * 4 + co4];
                #pragma unroll
                for (int p = 0; p < 4; ++p) acc2[co4][p] = bb;
            }
            for (int ci = 0; ci < 16; ++ci) {
                float in2[4][4];
                #pragma unroll
                for (int rr = 0; rr < 4; ++rr)
                    #pragma unroll
                    for (int m = 0; m < 2; ++m) {
                        float2 v = *(const float2*)&pools[ci * 144 + (2 * sr + rr) * 12 + 2 * sc + 2 * m];
                        in2[rr][2 * m] = v.x; in2[rr][2 * m + 1] = v.y;
                    }
                #pragma unroll
                for (int co4 = 0; co4 < 4; ++co4) {
                    const float* wp = &w2s[ci * 384 + (cog * 4 + co4) * 12];
                    float4 wa = *(const float4*)wp;
                    float4 wb = *(const float4*)(wp + 4);
                    float w8 = wp[8];
                    float wv[9] = {wa.x, wa.y, wa.z, wa.w, wb.x, wb.y, wb.z, wb.w, w8};
                    #pragma unroll
                    for (int rr2 = 0; rr2 < 2; ++rr2)
                        #pragma unroll
                        for (int cc2 = 0; cc2 < 2; ++cc2) {
                            float s = 0.f;
                            #pragma unroll
                            for (int u = 0; u < 3; ++u)
                                #pragma unroll
                                for (int v = 0; v < 3; ++v)
                                    s += in2[rr2 + u][cc2 + v] * wv[u * 3 + v];
                            acc2[co4][rr2 * 2 + cc2] += s;
                        }
                }
            }
            #pragma unroll
            for (int co4 = 0; co4 < 4; ++co4)
                #pragma unroll
                for (int rr2 = 0; rr2 < 2; ++rr2)
                    #pragma unroll
                    for (int cc2 = 0; cc2 < 2; ++cc2)
                        hbuf[(cog * 4 + co4) * 100 + (2 * sr + rr2) * 10 + (2 * sc + cc2)]
                            = fmaxf(acc2[co4][rr2 * 2 + cc2], 0.f);
        }
    }
    __syncthreads();

    // ---- h16 write + gate: logits = h @ gw + gb, softmax, top-3 renormalized
    float part[5] = {0, 0, 0, 0, 0};
    for (int k = t; k < 3200; k += 256) {
        float hv = hbuf[k];
        h16[(size_t)b * D_IN + k] = (_Float16)hv;
        const float* g = &gw[k * 5];
        part[0] += hv * g[0]; part[1] += hv * g[1]; part[2] += hv * g[2];
        part[3] += hv * g[3]; part[4] += hv * g[4];
    }
    int lane = t & 63, wv = t >> 6;
    #pragma unroll
    for (int e = 0; e < 5; ++e) {
        float v = part[e];
        for (int off = 32; off > 0; off >>= 1) v += __shfl_down(v, off, 64);
        if (lane == 0) red[wv][e] = v;
    }
    __syncthreads();
    if (t == 0) {
        float lg[5], p[5];
        float mx = -1e30f;
        for (int e = 0; e < 5; ++e) {
            lg[e] = red[0][e] + red[1][e] + red[2][e] + red[3][e] + gb[e];
            mx = fmaxf(mx, lg[e]);
        }
        float sum = 0.f;
        for (int e = 0; e < 5; ++e) { p[e] = expf(lg[e] - mx); sum += p[e]; }
        for (int e = 0; e < 5; ++e) p[e] /= sum;
        bool used[5] = {false, false, false, false, false};
        float out5[5] = {0, 0, 0, 0, 0};
        int ti[3]; float tv[3]; float tsum = 0.f;
        for (int jj = 0; jj < 3; ++jj) {
            int best = 0; float bv = -1.f;
            for (int e = 0; e < 5; ++e)
                if (!used[e] && p[e] > bv) { bv = p[e]; best = e; }
            used[best] = true; ti[jj] = best; tv[jj] = bv; tsum += bv;
        }
        for (int jj = 0; jj < 3; ++jj) out5[ti[jj]] = tv[jj] / tsum;
        for (int e = 0; e < 5; ++e) wfull[b * 5 + e] = out5[e];
    }
}

// ---------------- kernel 2: h1[e,b,n] = tanh(h @ e1_w[e] + b1[e])  (f16 MFMA GEMM)
// block tile 64(M) x 128(N), BK=32, 4 waves each 32x64
__global__ __launch_bounds__(256) void k_e1(
    const _Float16* __restrict__ h16, const _Float16* __restrict__ wT,
    const float* __restrict__ e1b, float* __restrict__ h1)
{
    __shared__ __align__(16) _Float16 As[64 * 32];
    __shared__ __align__(16) _Float16 Bs[128 * 32];
    int mt = blockIdx.x, e = blockIdx.y;
    int m0 = mt * 64;
    int t = threadIdx.x;
    int lane = t & 63, wv = t >> 6;
    int waveM = wv >> 1, waveN = wv & 1;
    int quad = lane >> 4, l16 = lane & 15;
    const _Float16* wbase = wT + (size_t)e * D_H * D_IN;
    f32x4 acc[2][4];
    #pragma unroll
    for (int i = 0; i < 2; ++i)
        #pragma unroll
        for (int j = 0; j < 4; ++j) acc[i][j] = (f32x4){0.f, 0.f, 0.f, 0.f};
    int arow = t >> 2, acol = (t & 3) * 8;   // 64 rows x 32 cols, 16B per thread
    for (int k0 = 0; k0 < D_IN; k0 += 32) {
        *(uint4*)(&As[arow * 32 + acol]) =
            *(const uint4*)(&h16[(size_t)(m0 + arow) * D_IN + k0 + acol]);
        *(uint4*)(&Bs[arow * 32 + acol]) =
            *(const uint4*)(&wbase[(size_t)arow * D_IN + k0 + acol]);
        *(uint4*)(&Bs[(arow + 64) * 32 + acol]) =
            *(const uint4*)(&wbase[(size_t)(arow + 64) * D_IN + k0 + acol]);
        __syncthreads();
        f16x8 a[2], bfr[4];
        #pragma unroll
        for (int ms = 0; ms < 2; ++ms)
            a[ms] = *(const f16x8*)(&As[(waveM * 32 + ms * 16 + l16) * 32 + quad * 8]);
        #pragma unroll
        for (int ns = 0; ns < 4; ++ns)
            bfr[ns] = *(const f16x8*)(&Bs[(waveN * 64 + ns * 16 + l16) * 32 + quad * 8]);
        #pragma unroll
        for (int ms = 0; ms < 2; ++ms)
            #pragma unroll
            for (int ns = 0; ns < 4; ++ns)
                acc[ms][ns] = __builtin_amdgcn_mfma_f32_16x16x32_f16(a[ms], bfr[ns], acc[ms][ns], 0, 0, 0);
        __syncthreads();
    }
    // epilogue: D row = quad*4 + reg, col = l16 (within 16x16 tile)
    #pragma unroll
    for (int ms = 0; ms < 2; ++ms) {
        int mbase = m0 + waveM * 32 + ms * 16 + quad * 4;
        #pragma unroll
        for (int ns = 0; ns < 4; ++ns) {
            int n = waveN * 64 + ns * 16 + l16;
            float bias = e1b[e * D_H + n];
            #pragma unroll
            for (int r = 0; r < 4; ++r) {
                int m = mbase + r;
                h1[((size_t)e * NB + m) * D_H + n] = tanhf(acc[ms][ns][r] + bias);
            }
        }
    }
}

// ---------------- kernel 3: h2 = tanh(h1 @ e2_w + b2); moe = sum_e w*h2; head softmax
__global__ __launch_bounds__(128) void k_moe(
    const float* __restrict__ h1, const float* __restrict__ wfull,
    const float* __restrict__ e2w, const float* __restrict__ e2b,
    const float* __restrict__ smw, const float* __restrict__ smb,
    float* __restrict__ out)
{
    __shared__ float wlds[64][128];   // half of e2_w[e], K-split
    __shared__ float h1s[TOK][128];
    __shared__ float wf[TOK][5];
    __shared__ float lg[TOK][10];
    int b0 = blockIdx.x * TOK;
    int n = threadIdx.x;   // 0..127
    for (int i = n; i < TOK * 5; i += 128)
        wf[i / 5][i % 5] = wfull[(size_t)(b0 + i / 5) * 5 + (i % 5)];
    float moe[TOK];
    #pragma unroll
    for (int tt = 0; tt < TOK; ++tt) moe[tt] = 0.f;
    __syncthreads();
    for (int e = 0; e < NE; ++e) {
        bool any = false;
        for (int tt = 0; tt < TOK; ++tt) any = any || (wf[tt][e] > 0.f);
        if (!any) continue;                      // uniform across block
        float pre[TOK];
        float bias = e2b[e * D_H + n];
        #pragma unroll
        for (int tt = 0; tt < TOK; ++tt) pre[tt] = bias;
        __syncthreads();                          // prior users of h1s/wlds done
        for (int tt = 0; tt < TOK; ++tt)
            h1s[tt][n] = h1[((size_t)e * NB + b0 + tt) * D_H + n];
        for (int kh = 0; kh < 2; ++kh) {
            if (kh) __syncthreads();              // compute of kh=0 done before reload
            for (int k = 0; k < 64; ++k)
                wlds[k][n] = e2w[(size_t)e * D_H * D_H + (kh * 64 + k) * D_H + n];
            __syncthreads();
            for (int tt = 0; tt < TOK; ++tt) {
                if (!(wf[tt][e] > 0.f)) continue; // uniform (wf same for all threads)
                #pragma unroll 8
                for (int k = 0; k < 64; ++k)
                    pre[tt] += h1s[tt][kh * 64 + k] * wlds[k][n];
            }
        }
        #pragma unroll
        for (int tt = 0; tt < TOK; ++tt)
            if (wf[tt][e] > 0.f) moe[tt] += wf[tt][e] * tanhf(pre[tt]);
    }
    // head: logits = moe @ smw + smb, softmax over 10
    __syncthreads();
    float* moes = &wlds[0][0];                    // reuse LDS
    for (int tt = 0; tt < TOK; ++tt) moes[tt * 128 + n] = moe[tt];
    __syncthreads();
    for (int i = n; i < TOK * 10; i += 128) {
        int tt = i / 10, c = i - (i / 10) * 10;
        float s = smb[c];
        for (int kk = 0; kk < 128; ++kk) s += moes[tt * 128 + kk] * smw[kk * 10 + c];
        lg[tt][c] = s;
    }
    __syncthreads();
    if (n < TOK) {
        float mx = -1e30f;
        for (int c = 0; c < 10; ++c) mx = fmaxf(mx, lg[n][c]);
        float s = 0.f, ex[10];
        for (int c = 0; c < 10; ++c) { ex[c] = expf(lg[n][c] - mx); s += ex[c]; }
        float inv = 1.f / s;
        for (int c = 0; c < 10; ++c) out[(size_t)(b0 + n) * 10 + c] = ex[c] * inv;
    }
}

extern "C" void kernel_launch(void* const* d_in, const int* in_sizes, int n_in,
                              void* d_out, int out_size, void* d_ws, size_t ws_size,
                              hipStream_t stream)
{
    const float* x   = (const float*)d_in[0];
    const float* c1w = (const float*)d_in[1];
    const float* c1b = (const float*)d_in[2];
    const float* c2w = (const float*)d_in[3];
    const float* c2b = (const float*)d_in[4];
    const float* gw  = (const float*)d_in[5];
    const float* gb  = (const float*)d_in[6];
    const float* e1w = (const float*)d_in[7];
    const float* e1b = (const float*)d_in[8];
    const float* e2w = (const float*)d_in[9];
    const float* e2b = (const float*)d_in[10];
    const float* smw = (const float*)d_in[11];
    const float* smb = (const float*)d_in[12];
    float* out = (float*)d_out;

    // workspace carve (≈78 MB total)
    char* ws = (char*)d_ws;
    size_t off = 0;
    auto alloc = [&](size_t bytes) {
        void* p = ws + off;
        off += (bytes + 255) & ~(size_t)255;
        return p;
    };
    _Float16* h16 = (_Float16*)alloc((size_t)NB * D_IN * 2);          // 52.4 MB
    _Float16* wT  = (_Float16*)alloc((size_t)NE * D_H * D_IN * 2);    // 4.1 MB
    float* wfull  = (float*)alloc((size_t)NB * NE * 4);               // 0.16 MB
    float* h1     = (float*)alloc((size_t)NE * NB * D_H * 4);         // 21 MB

    k_wconv<<<dim3(NE, D_IN / 64, D_H / 64), 256, 0, stream>>>(e1w, wT);
    k_feat<<<dim3(NB), 256, 0, stream>>>(x, c1w, c1b, c2w, c2b, gw, gb, h16, wfull);
    k_e1<<<dim3(NB / 64, NE), 256, 0, stream>>>(h16, wT, e1b, h1);
    k_moe<<<dim3(NB / TOK), 128, 0, stream>>>(h1, wfull, e2w, e2b, smw, smb, out);
}

// Round 3
// 413.584 us; speedup vs baseline: 3.0752x; 1.1279x over previous
//
#include <hip/hip_runtime.h>
#include <hip/hip_bf16.h>
#include <hip/hip_fp16.h>

#define NB 8192
#define D_IN 3200
#define D_H 128
#define NE 5

typedef _Float16 f16x8 __attribute__((ext_vector_type(8)));
typedef float f32x4 __attribute__((ext_vector_type(4)));

// ---------------- kernel 0: e1_w [5][3200][128] f32 -> f16 transposed [5][128][3200]
__global__ __launch_bounds__(256) void k_wconv(const float* __restrict__ e1w,
                                               _Float16* __restrict__ wT) {
    __shared__ float tile[64][65];
    int e = blockIdx.x;
    int k0 = blockIdx.y * 64;
    int n0 = blockIdx.z * 64;
    const float* src = e1w + (size_t)e * D_IN * D_H;
    _Float16* dst = wT + (size_t)e * D_H * D_IN;
    int t = threadIdx.x;
    for (int i = 0; i < 16; ++i) {
        int idx = t + i * 256;
        int kr = idx >> 6, nc = idx & 63;
        tile[kr][nc] = src[(size_t)(k0 + kr) * D_H + n0 + nc];
    }
    __syncthreads();
    for (int i = 0; i < 16; ++i) {
        int idx = t + i * 256;
        int nr = idx >> 6, kc = idx & 63;
        dst[(size_t)(n0 + nr) * D_IN + k0 + kc] = (_Float16)tile[kc][nr];
    }
}

// ---------------- kernel 0b: e2_w [5][128][128] f32 -> f16 transposed [5][128][128] (n,k)
__global__ __launch_bounds__(256) void k_wprep2(const float* __restrict__ e2w,
                                                _Float16* __restrict__ e2T) {
    __shared__ float tile[64][65];
    int e = blockIdx.x;
    int k0 = blockIdx.y * 64;
    int n0 = blockIdx.z * 64;
    const float* src = e2w + (size_t)e * D_H * D_H;
    _Float16* dst = e2T + (size_t)e * D_H * D_H;
    int t = threadIdx.x;
    for (int i = 0; i < 16; ++i) {
        int idx = t + i * 256;
        int kr = idx >> 6, nc = idx & 63;
        tile[kr][nc] = src[(size_t)(k0 + kr) * D_H + n0 + nc];
    }
    __syncthreads();
    for (int i = 0; i < 16; ++i) {
        int idx = t + i * 256;
        int nr = idx >> 6, kc = idx & 63;
        dst[(size_t)(n0 + nr) * D_H + k0 + kc] = (_Float16)tile[kc][nr];
    }
}

// ---------------- kernel 1: conv1+pool fused -> conv2 (+fused gate partials) -> h16 + top-3 gate
// launch_bounds(256,4): VGPR cap 128 so conv windows stay in registers; LDS ~39KB -> 4 blocks/CU
__global__ __launch_bounds__(256, 4) void k_feat(
    const float* __restrict__ x, const float* __restrict__ c1w, const float* __restrict__ c1b,
    const float* __restrict__ c2w, const float* __restrict__ c2b,
    const float* __restrict__ gw, const float* __restrict__ gb,
    _Float16* __restrict__ h16, float* __restrict__ wfull)
{
    __shared__ __align__(16) float xs[784];          // 3136 B
    __shared__ __align__(16) float c1wsP[16 * 28];   // 1792 B (25 padded to 28)
    __shared__ __align__(16) float w2s[16 * 32 * 12];// 24576 B  [ci][co][12] (9 padded)
    __shared__ __align__(16) float pools[16 * 144];  // 9216 B   [ci][12][12]
    __shared__ float red[4][8];
    int b = blockIdx.x;
    int t = threadIdx.x;

    // ---- stage inputs/weights
    for (int i = t; i < 784; i += 256) xs[i] = x[(size_t)b * 784 + i];
    for (int i = t; i < 400; i += 256) {
        int c = i / 25, q = i - c * 25;
        c1wsP[c * 28 + q] = c1w[i];
    }
    for (int i = t; i < 4608; i += 256) {
        int co = i / 144, rem = i - co * 144;
        int ci = rem / 9, q = rem - ci * 9;
        w2s[ci * 384 + co * 12 + q] = c2w[i];
    }
    __syncthreads();

    // ---- conv1 (5x5 valid, relu) fused with 2x2 maxpool -> pools[16][12][12]
    {
        int c = t >> 4;            // channel 0..15
        int tile = t & 15;
        int tr = tile >> 2, tc = tile & 3;   // 3x3 pooled tile origin (3tr, 3tc)
        float w1r[25];
        #pragma unroll
        for (int q = 0; q < 6; ++q) {
            float4 v4 = *(const float4*)&c1wsP[c * 28 + q * 4];
            w1r[q * 4 + 0] = v4.x; w1r[q * 4 + 1] = v4.y;
            w1r[q * 4 + 2] = v4.z; w1r[q * 4 + 3] = v4.w;
        }
        w1r[24] = c1wsP[c * 28 + 24];
        float bias1 = c1b[c];
        float win[5][10];
        float pacc[3][3];
        #pragma unroll
        for (int i = 0; i < 3; ++i)
            #pragma unroll
            for (int j = 0; j < 3; ++j) pacc[i][j] = 0.f;
        int r0 = 6 * tr, col0 = 6 * tc;
        #pragma unroll
        for (int cr = 0; cr < 6; ++cr) {
            if (cr == 0) {
                #pragma unroll
                for (int rr = 0; rr < 5; ++rr)
                    #pragma unroll
                    for (int m = 0; m < 5; ++m) {
                        float2 v = *(const float2*)&xs[(r0 + rr) * 28 + col0 + 2 * m];
                        win[rr][2 * m] = v.x; win[rr][2 * m + 1] = v.y;
                    }
            } else {
                int dstr = (cr + 4) % 5;
                #pragma unroll
                for (int m = 0; m < 5; ++m) {
                    float2 v = *(const float2*)&xs[(r0 + cr + 4) * 28 + col0 + 2 * m];
                    win[dstr][2 * m] = v.x; win[dstr][2 * m + 1] = v.y;
                }
            }
            #pragma unroll
            for (int oc = 0; oc < 6; ++oc) {
                float s = bias1;
                #pragma unroll
                for (int u = 0; u < 5; ++u)
                    #pragma unroll
                    for (int v = 0; v < 5; ++v)
                        s += win[(cr + u) % 5][oc + v] * w1r[u * 5 + v];
                s = fmaxf(s, 0.f);
                pacc[cr >> 1][oc >> 1] = fmaxf(pacc[cr >> 1][oc >> 1], s);
            }
        }
        #pragma unroll
        for (int i = 0; i < 3; ++i)
            #pragma unroll
            for (int j = 0; j < 3; ++j)
                pools[c * 144 + (3 * tr + i) * 12 + (3 * tc + j)] = pacc[i][j];
    }
    __syncthreads();

    // ---- conv2 (3x3 valid over 16 ci, relu) -> h16 global + fused gate partials
    float part[5] = {0, 0, 0, 0, 0};
    {
        int cog = t >> 5;          // 0..7 -> co = 4*cog..4*cog+3
        int sb = t & 31;           // spatial 2x2 block, 25 active
        if (sb < 25) {
            int sr = sb / 5, sc = sb - (sb / 5) * 5;   // block origin (2sr, 2sc)
            float acc2[4][4];
            #pragma unroll
            for (int co4 = 0; co4 < 4; ++co4) {
                float bb = c2b[cog * 4 + co4];
                #pragma unroll
                for (int p = 0; p < 4; ++p) acc2[co4][p] = bb;
            }
            for (int ci = 0; ci < 16; ++ci) {
                float in2[4][4];
                #pragma unroll
                for (int rr = 0; rr < 4; ++rr)
                    #pragma unroll
                    for (int m = 0; m < 2; ++m) {
                        float2 v = *(const float2*)&pools[ci * 144 + (2 * sr + rr) * 12 + 2 * sc + 2 * m];
                        in2[rr][2 * m] = v.x; in2[rr][2 * m + 1] = v.y;
                    }
                #pragma unroll
                for (int co4 = 0; co4 < 4; ++co4) {
                    const float* wp = &w2s[ci * 384 + (cog * 4 + co4) * 12];
                    float4 wa = *(const float4*)wp;
                    float4 wb = *(const float4*)(wp + 4);
                    float w8 = wp[8];
                    float wv[9] = {wa.x, wa.y, wa.z, wa.w, wb.x, wb.y, wb.z, wb.w, w8};
                    #pragma unroll
                    for (int rr2 = 0; rr2 < 2; ++rr2)
                        #pragma unroll
                        for (int cc2 = 0; cc2 < 2; ++cc2) {
                            float s = 0.f;
                            #pragma unroll
                            for (int u = 0; u < 3; ++u)
                                #pragma unroll
                                for (int v = 0; v < 3; ++v)
                                    s += in2[rr2 + u][cc2 + v] * wv[u * 3 + v];
                            acc2[co4][rr2 * 2 + cc2] += s;
                        }
                }
            }
            #pragma unroll
            for (int co4 = 0; co4 < 4; ++co4)
                #pragma unroll
                for (int rr2 = 0; rr2 < 2; ++rr2)
                    #pragma unroll
                    for (int cc2 = 0; cc2 < 2; ++cc2) {
                        int idx = (cog * 4 + co4) * 100 + (2 * sr + rr2) * 10 + (2 * sc + cc2);
                        float hv = fmaxf(acc2[co4][rr2 * 2 + cc2], 0.f);
                        h16[(size_t)b * D_IN + idx] = (_Float16)hv;
                        const float* g = &gw[idx * 5];
                        part[0] += hv * g[0]; part[1] += hv * g[1]; part[2] += hv * g[2];
                        part[3] += hv * g[3]; part[4] += hv * g[4];
                    }
        }
    }

    // ---- gate reduce: softmax, top-3 renormalized
    int lane = t & 63, wv = t >> 6;
    #pragma unroll
    for (int e = 0; e < 5; ++e) {
        float v = part[e];
        for (int off = 32; off > 0; off >>= 1) v += __shfl_down(v, off, 64);
        if (lane == 0) red[wv][e] = v;
    }
    __syncthreads();
    if (t == 0) {
        float lg[5], p[5];
        float mx = -1e30f;
        for (int e = 0; e < 5; ++e) {
            lg[e] = red[0][e] + red[1][e] + red[2][e] + red[3][e] + gb[e];
            mx = fmaxf(mx, lg[e]);
        }
        float sum = 0.f;
        for (int e = 0; e < 5; ++e) { p[e] = expf(lg[e] - mx); sum += p[e]; }
        for (int e = 0; e < 5; ++e) p[e] /= sum;
        bool used[5] = {false, false, false, false, false};
        float out5[5] = {0, 0, 0, 0, 0};
        int ti[3]; float tv[3]; float tsum = 0.f;
        for (int jj = 0; jj < 3; ++jj) {
            int best = 0; float bv = -1.f;
            for (int e = 0; e < 5; ++e)
                if (!used[e] && p[e] > bv) { bv = p[e]; best = e; }
            used[best] = true; ti[jj] = best; tv[jj] = bv; tsum += bv;
        }
        for (int jj = 0; jj < 3; ++jj) out5[ti[jj]] = tv[jj] / tsum;
        for (int e = 0; e < 5; ++e) wfull[b * 5 + e] = out5[e];
    }
}

// ---------------- kernel 2: fused expert pipeline.
// grid (128 mtiles, 5 experts). Per block: e1 MFMA (64x128, K=3200) -> tanh ->
// h1 tile in LDS -> e2 MFMA (K=128) -> tanh * gate weight -> atomicAdd into moe.
union SLds {
    struct { _Float16 As[64 * 40]; _Float16 Bs[128 * 40]; } p1;  // e1 staging (pad 40)
    _Float16 e2ws[128 * 136];                                    // e2 weights (pad 136)
};

__global__ __launch_bounds__(256, 3) void k_e1e2(
    const _Float16* __restrict__ h16, const _Float16* __restrict__ wT,
    const _Float16* __restrict__ e2T,
    const float* __restrict__ e1b, const float* __restrict__ e2b,
    const float* __restrict__ wfull, float* __restrict__ moe)
{
    __shared__ SLds u;                                  // 34816 B
    __shared__ __align__(16) _Float16 h1s[64 * 136];    // 17408 B
    __shared__ float wf5[5 * 64];                       // 1280 B
    int m0 = blockIdx.x * 64;
    int e = blockIdx.y;
    int t = threadIdx.x;
    int lane = t & 63, wv = t >> 6;
    int waveM = wv >> 1, waveN = wv & 1;
    int quad = lane >> 4, l16 = lane & 15;

    for (int i = t; i < 320; i += 256)
        wf5[i] = wfull[(size_t)(m0 + (i & 63)) * 5 + (i >> 6)];

    const _Float16* wbase = wT + (size_t)e * D_H * D_IN;
    f32x4 acc[2][4];
    #pragma unroll
    for (int i = 0; i < 2; ++i)
        #pragma unroll
        for (int j = 0; j < 4; ++j) acc[i][j] = (f32x4){0.f, 0.f, 0.f, 0.f};

    int arow = t >> 2, acol = (t & 3) * 8;
    for (int k0 = 0; k0 < D_IN; k0 += 32) {
        *(uint4*)(&u.p1.As[arow * 40 + acol]) =
            *(const uint4*)(&h16[(size_t)(m0 + arow) * D_IN + k0 + acol]);
        *(uint4*)(&u.p1.Bs[arow * 40 + acol]) =
            *(const uint4*)(&wbase[(size_t)arow * D_IN + k0 + acol]);
        *(uint4*)(&u.p1.Bs[(arow + 64) * 40 + acol]) =
            *(const uint4*)(&wbase[(size_t)(arow + 64) * D_IN + k0 + acol]);
        __syncthreads();
        f16x8 a[2], bfr[4];
        #pragma unroll
        for (int ms = 0; ms < 2; ++ms)
            a[ms] = *(const f16x8*)(&u.p1.As[(waveM * 32 + ms * 16 + l16) * 40 + quad * 8]);
        #pragma unroll
        for (int ns = 0; ns < 4; ++ns)
            bfr[ns] = *(const f16x8*)(&u.p1.Bs[(waveN * 64 + ns * 16 + l16) * 40 + quad * 8]);
        #pragma unroll
        for (int ms = 0; ms < 2; ++ms)
            #pragma unroll
            for (int ns = 0; ns < 4; ++ns)
                acc[ms][ns] = __builtin_amdgcn_mfma_f32_16x16x32_f16(a[ms], bfr[ns], acc[ms][ns], 0, 0, 0);
        __syncthreads();
    }

    // h1 = tanh(acc + e1b) -> LDS (f16), C/D layout: row=quad*4+r, col=l16
    #pragma unroll
    for (int ms = 0; ms < 2; ++ms) {
        int rbase = waveM * 32 + ms * 16 + quad * 4;
        #pragma unroll
        for (int ns = 0; ns < 4; ++ns) {
            int n = waveN * 64 + ns * 16 + l16;
            float bias = e1b[e * D_H + n];
            #pragma unroll
            for (int r = 0; r < 4; ++r)
                h1s[(rbase + r) * 136 + n] = (_Float16)tanhf(acc[ms][ns][r] + bias);
        }
    }
    __syncthreads();   // h1s visible; As/Bs reads all done -> safe to overwrite with e2ws

    // stage e2_w^T [n][k] f16 -> LDS
    {
        int r2 = t >> 1, c2 = (t & 1) * 64;
        const _Float16* src = e2T + (size_t)e * D_H * D_H + (size_t)r2 * D_H + c2;
        #pragma unroll
        for (int i = 0; i < 8; ++i)
            *(uint4*)(&u.e2ws[r2 * 136 + c2 + i * 8]) = *(const uint4*)(src + i * 8);
    }
    __syncthreads();

    // e2 MFMA: h1[64x128] @ e2w[128x128]
    f32x4 acc2[2][4];
    #pragma unroll
    for (int i = 0; i < 2; ++i)
        #pragma unroll
        for (int j = 0; j < 4; ++j) acc2[i][j] = (f32x4){0.f, 0.f, 0.f, 0.f};
    #pragma unroll
    for (int kc = 0; kc < 4; ++kc) {
        f16x8 a2[2], b2[4];
        #pragma unroll
        for (int ms = 0; ms < 2; ++ms)
            a2[ms] = *(const f16x8*)(&h1s[(waveM * 32 + ms * 16 + l16) * 136 + kc * 32 + quad * 8]);
        #pragma unroll
        for (int ns = 0; ns < 4; ++ns)
            b2[ns] = *(const f16x8*)(&u.e2ws[(waveN * 64 + ns * 16 + l16) * 136 + kc * 32 + quad * 8]);
        #pragma unroll
        for (int ms = 0; ms < 2; ++ms)
            #pragma unroll
            for (int ns = 0; ns < 4; ++ns)
                acc2[ms][ns] = __builtin_amdgcn_mfma_f32_16x16x32_f16(a2[ms], b2[ns], acc2[ms][ns], 0, 0, 0);
    }

    // h2 = tanh(acc2 + e2b); weighted atomic combine
    #pragma unroll
    for (int ms = 0; ms < 2; ++ms) {
        int rbase = waveM * 32 + ms * 16 + quad * 4;
        #pragma unroll
        for (int ns = 0; ns < 4; ++ns) {
            int n = waveN * 64 + ns * 16 + l16;
            float bias = e2b[e * D_H + n];
            #pragma unroll
            for (int r = 0; r < 4; ++r) {
                int row = rbase + r;
                float w = wf5[e * 64 + row];
                if (w != 0.f) {
                    float h2 = tanhf(acc2[ms][ns][r] + bias);
                    unsafeAtomicAdd(&moe[(size_t)(m0 + row) * D_H + n], w * h2);
                }
            }
        }
    }
}

// ---------------- kernel 3: head: logits = moe @ smw + smb, softmax -> out
__global__ __launch_bounds__(256) void k_head(
    const float* __restrict__ moe, const float* __restrict__ smw,
    const float* __restrict__ smb, float* __restrict__ out)
{
    __shared__ float moesT[128 * 66];   // [k][row], pad 66
    __shared__ float smws[1280];
    __shared__ float smbs[16];
    __shared__ float lg[64 * 12];
    int b0 = blockIdx.x * 64;
    int t = threadIdx.x;
    for (int i = t; i < 1280; i += 256) smws[i] = smw[i];
    if (t < 10) smbs[t] = smb[t];
    {
        int row = t >> 2, cb = (t & 3) * 32;
        #pragma unroll
        for (int i = 0; i < 8; ++i) {
            float4 v = *(const float4*)&moe[(size_t)(b0 + row) * D_H + cb + i * 4];
            moesT[(cb + i * 4 + 0) * 66 + row] = v.x;
            moesT[(cb + i * 4 + 1) * 66 + row] = v.y;
            moesT[(cb + i * 4 + 2) * 66 + row] = v.z;
            moesT[(cb + i * 4 + 3) * 66 + row] = v.w;
        }
    }
    __syncthreads();
    {
        int row = t & 63, grp = t >> 6;
        int c0 = grp, c1 = grp + 4, c2 = grp + 8;
        float s0 = 0.f, s1 = 0.f, s2 = 0.f;
        for (int k = 0; k < 128; ++k) {
            float m = moesT[k * 66 + row];
            s0 += m * smws[k * 10 + c0];
            s1 += m * smws[k * 10 + c1];
            if (c2 < 10) s2 += m * smws[k * 10 + c2];
        }
        lg[row * 12 + c0] = s0 + smbs[c0];
        lg[row * 12 + c1] = s1 + smbs[c1];
        if (c2 < 10) lg[row * 12 + c2] = s2 + smbs[c2];
    }
    __syncthreads();
    if (t < 64) {
        float mx = -1e30f;
        for (int c = 0; c < 10; ++c) mx = fmaxf(mx, lg[t * 12 + c]);
        float s = 0.f, ex[10];
        for (int c = 0; c < 10; ++c) { ex[c] = expf(lg[t * 12 + c] - mx); s += ex[c]; }
        float inv = 1.f / s;
        for (int c = 0; c < 10; ++c) out[(size_t)(b0 + t) * 10 + c] = ex[c] * inv;
    }
}

extern "C" void kernel_launch(void* const* d_in, const int* in_sizes, int n_in,
                              void* d_out, int out_size, void* d_ws, size_t ws_size,
                              hipStream_t stream)
{
    const float* x   = (const float*)d_in[0];
    const float* c1w = (const float*)d_in[1];
    const float* c1b = (const float*)d_in[2];
    const float* c2w = (const float*)d_in[3];
    const float* c2b = (const float*)d_in[4];
    const float* gw  = (const float*)d_in[5];
    const float* gb  = (const float*)d_in[6];
    const float* e1w = (const float*)d_in[7];
    const float* e1b = (const float*)d_in[8];
    const float* e2w = (const float*)d_in[9];
    const float* e2b = (const float*)d_in[10];
    const float* smw = (const float*)d_in[11];
    const float* smb = (const float*)d_in[12];
    float* out = (float*)d_out;

    char* ws = (char*)d_ws;
    size_t off = 0;
    auto alloc = [&](size_t bytes) {
        void* p = ws + off;
        off += (bytes + 255) & ~(size_t)255;
        return p;
    };
    _Float16* h16 = (_Float16*)alloc((size_t)NB * D_IN * 2);          // 52.4 MB
    _Float16* wT  = (_Float16*)alloc((size_t)NE * D_H * D_IN * 2);    // 4.1 MB
    _Float16* e2T = (_Float16*)alloc((size_t)NE * D_H * D_H * 2);     // 0.16 MB
    float* wfull  = (float*)alloc((size_t)NB * NE * 4);               // 0.16 MB
    float* moe    = (float*)alloc((size_t)NB * D_H * 4);              // 4.2 MB

    hipMemsetAsync(moe, 0, (size_t)NB * D_H * 4, stream);
    k_wconv<<<dim3(NE, D_IN / 64, D_H / 64), 256, 0, stream>>>(e1w, wT);
    k_wprep2<<<dim3(NE, 2, 2), 256, 0, stream>>>(e2w, e2T);
    k_feat<<<dim3(NB), 256, 0, stream>>>(x, c1w, c1b, c2w, c2b, gw, gb, h16, wfull);
    k_e1e2<<<dim3(NB / 64, NE), 256, 0, stream>>>(h16, wT, e2T, e1b, e2b, wfull, moe);
    k_head<<<dim3(NB / 64), 256, 0, stream>>>(moe, smw, smb, out);
}

// Round 4
// 355.927 us; speedup vs baseline: 3.5734x; 1.1620x over previous
//
#include <hip/hip_runtime.h>
#include <hip/hip_bf16.h>
#include <hip/hip_fp16.h>

#define NB 8192
#define D_IN 3200
#define D_H 128
#define NE 5

typedef _Float16 f16x8 __attribute__((ext_vector_type(8)));
typedef _Float16 f16x4 __attribute__((ext_vector_type(4)));
typedef float f32x4 __attribute__((ext_vector_type(4)));

// ---------------- kernel 0: e1_w [5][3200][128] f32 -> f16 transposed [5][128][3200]
__global__ __launch_bounds__(256) void k_wconv(const float* __restrict__ e1w,
                                               _Float16* __restrict__ wT) {
    __shared__ float tile[64][65];
    int e = blockIdx.x;
    int k0 = blockIdx.y * 64;
    int n0 = blockIdx.z * 64;
    const float* src = e1w + (size_t)e * D_IN * D_H;
    _Float16* dst = wT + (size_t)e * D_H * D_IN;
    int t = threadIdx.x;
    for (int i = 0; i < 16; ++i) {
        int idx = t + i * 256;
        int kr = idx >> 6, nc = idx & 63;
        tile[kr][nc] = src[(size_t)(k0 + kr) * D_H + n0 + nc];
    }
    __syncthreads();
    for (int i = 0; i < 16; ++i) {
        int idx = t + i * 256;
        int nr = idx >> 6, kc = idx & 63;
        dst[(size_t)(n0 + nr) * D_IN + k0 + kc] = (_Float16)tile[kc][nr];
    }
}

// ---------------- kernel 0b: e2_w [5][128][128] f32 -> f16 transposed [5][128][128] (n,k)
__global__ __launch_bounds__(256) void k_wprep2(const float* __restrict__ e2w,
                                                _Float16* __restrict__ e2T) {
    __shared__ float tile[64][65];
    int e = blockIdx.x;
    int k0 = blockIdx.y * 64;
    int n0 = blockIdx.z * 64;
    const float* src = e2w + (size_t)e * D_H * D_H;
    _Float16* dst = e2T + (size_t)e * D_H * D_H;
    int t = threadIdx.x;
    for (int i = 0; i < 16; ++i) {
        int idx = t + i * 256;
        int kr = idx >> 6, nc = idx & 63;
        tile[kr][nc] = src[(size_t)(k0 + kr) * D_H + n0 + nc];
    }
    __syncthreads();
    for (int i = 0; i < 16; ++i) {
        int idx = t + i * 256;
        int nr = idx >> 6, kc = idx & 63;
        dst[(size_t)(n0 + nr) * D_H + k0 + kc] = (_Float16)tile[kc][nr];
    }
}

// ---------------- kernel 1: conv1+pool (VALU) -> conv2 via shifted-GEMM MFMA -> h16 + gate
// pcl: pooled maps channel-last [pos(12x12)][16ci], hi/lo f16 split so gate logits stay
// f32-exact (top-3 selection is discontinuous; f16-only pools risk tie flips vs ref).
// conv2 K = 10 shifts x 16 ci = 160 (shift 9 dummy, B=0); 3 passes: ah*bh + ah*bl + al*bh.
#define PCL_S 24   // row stride in halves (48B: keeps f16x8 reads 16B-aligned, 2-way-free banks)
__global__ __launch_bounds__(256, 3) void k_feat(
    const float* __restrict__ x, const float* __restrict__ c1w, const float* __restrict__ c1b,
    const float* __restrict__ c2w, const float* __restrict__ c2b,
    const float* __restrict__ gw, const float* __restrict__ gb,
    _Float16* __restrict__ h16, float* __restrict__ wfull)
{
    __shared__ __align__(16) float xs[784];            // 3136 B
    __shared__ __align__(16) float c1wsP[16 * 28];     // 1792 B
    __shared__ __align__(16) _Float16 b2h[32 * 160];   // 10240 B [co][s*16+ci] hi
    __shared__ __align__(16) _Float16 b2l[32 * 160];   // 10240 B lo
    __shared__ __align__(16) _Float16 pclh[144 * PCL_S]; // 6912 B [pos][ci] hi
    __shared__ __align__(16) _Float16 pcll[144 * PCL_S]; // 6912 B lo
    __shared__ float red[4][8];
    int b = blockIdx.x;
    int t = threadIdx.x;

    // ---- stage x, conv1 weights, conv2 weights (hi/lo f16)
    for (int i = t; i < 784; i += 256) xs[i] = x[(size_t)b * 784 + i];
    for (int i = t; i < 400; i += 256) {
        int c = i / 25, q = i - c * 25;
        c1wsP[c * 28 + q] = c1w[i];
    }
    for (int i = t; i < 5120; i += 256) {      // 32co x 160k
        int co = i / 160, k = i - co * 160;
        int s = k >> 4, ci = k & 15;
        float v = (s == 9) ? 0.f : c2w[(co * 16 + ci) * 9 + s];
        _Float16 vh = (_Float16)v;
        b2h[i] = vh;
        b2l[i] = (_Float16)(v - (float)vh);
    }
    __syncthreads();

    // ---- conv1 (5x5 valid, relu) fused with 2x2 maxpool -> pcl (channel-last, hi/lo)
    {
        int c = t >> 4;            // channel 0..15
        int tile = t & 15;
        int tr = tile >> 2, tc = tile & 3;   // 3x3 pooled tile origin (3tr, 3tc)
        float w1r[25];
        #pragma unroll
        for (int q = 0; q < 6; ++q) {
            float4 v4 = *(const float4*)&c1wsP[c * 28 + q * 4];
            w1r[q * 4 + 0] = v4.x; w1r[q * 4 + 1] = v4.y;
            w1r[q * 4 + 2] = v4.z; w1r[q * 4 + 3] = v4.w;
        }
        w1r[24] = c1wsP[c * 28 + 24];
        float bias1 = c1b[c];
        float win[5][10];
        float pacc[3][3];
        #pragma unroll
        for (int i = 0; i < 3; ++i)
            #pragma unroll
            for (int j = 0; j < 3; ++j) pacc[i][j] = 0.f;
        int r0 = 6 * tr, col0 = 6 * tc;
        #pragma unroll
        for (int cr = 0; cr < 6; ++cr) {
            if (cr == 0) {
                #pragma unroll
                for (int rr = 0; rr < 5; ++rr)
                    #pragma unroll
                    for (int m = 0; m < 5; ++m) {
                        float2 v = *(const float2*)&xs[(r0 + rr) * 28 + col0 + 2 * m];
                        win[rr][2 * m] = v.x; win[rr][2 * m + 1] = v.y;
                    }
            } else {
                int dstr = (cr + 4) % 5;
                #pragma unroll
                for (int m = 0; m < 5; ++m) {
                    float2 v = *(const float2*)&xs[(r0 + cr + 4) * 28 + col0 + 2 * m];
                    win[dstr][2 * m] = v.x; win[dstr][2 * m + 1] = v.y;
                }
            }
            #pragma unroll
            for (int oc = 0; oc < 6; ++oc) {
                float s = bias1;
                #pragma unroll
                for (int u = 0; u < 5; ++u)
                    #pragma unroll
                    for (int v = 0; v < 5; ++v)
                        s += win[(cr + u) % 5][oc + v] * w1r[u * 5 + v];
                s = fmaxf(s, 0.f);
                pacc[cr >> 1][oc >> 1] = fmaxf(pacc[cr >> 1][oc >> 1], s);
            }
        }
        #pragma unroll
        for (int i = 0; i < 3; ++i)
            #pragma unroll
            for (int j = 0; j < 3; ++j) {
                int pos = (3 * tr + i) * 12 + (3 * tc + j);
                float v = pacc[i][j];
                _Float16 vh = (_Float16)v;
                pclh[pos * PCL_S + c] = vh;
                pcll[pos * PCL_S + c] = (_Float16)(v - (float)vh);
            }
    }
    __syncthreads();

    // ---- conv2 via MFMA: 7 m-tiles (o=pos idx, 100 valid of 112) x 2 n-tiles (32 co)
    float part[5] = {0, 0, 0, 0, 0};
    int lane = t & 63, wv = t >> 6;
    int quad = lane >> 4, l16 = lane & 15;
    int quadh = quad >> 1, quadl = quad & 1;
    for (int p = wv; p < 14; p += 4) {
        int mt = p >> 1, nt = p & 1;
        int o_a = mt * 16 + l16;
        int o_cl = o_a < 100 ? o_a : 99;
        int pb = (o_cl / 10) * 12 + (o_cl % 10);   // base pos in 12x12 grid
        int co = nt * 16 + l16;
        f32x4 acc = (f32x4){0.f, 0.f, 0.f, 0.f};
        const _Float16* Ap[3] = {pclh, pclh, pcll};
        const _Float16* Bp[3] = {b2h, b2l, b2h};
        #pragma unroll
        for (int pass = 0; pass < 3; ++pass) {
            #pragma unroll
            for (int kc = 0; kc < 5; ++kc) {
                // shift offsets: s = 2*kc + quadh; off = (s/3)*12 + s%3, s==9 -> 0 (B zero)
                const int offA[5] = {0, 2, 13, 24, 26};   // s = 0,2,4,6,8
                const int offB[5] = {1, 12, 14, 25, 0};   // s = 1,3,5,7,9
                int off = quadh ? offB[kc] : offA[kc];
                f16x8 a = *(const f16x8*)&Ap[pass][(pb + off) * PCL_S + quadl * 8];
                f16x8 bb = *(const f16x8*)&Bp[pass][co * 160 + kc * 32 + quad * 8];
                acc = __builtin_amdgcn_mfma_f32_16x16x32_f16(a, bb, acc, 0, 0, 0);
            }
        }
        // epilogue: C/D row=quad*4+r (= output pos o), col=l16 (= co)
        if (mt < 6 || quad == 0) {             // o0..o0+3 all < 100
            int o0 = mt * 16 + quad * 4;
            float bco = c2b[co];
            f16x4 st;
            #pragma unroll
            for (int r = 0; r < 4; ++r) {
                float hv = fmaxf(acc[r] + bco, 0.f);
                st[r] = (_Float16)hv;
                const float* g = &gw[(co * 100 + o0 + r) * 5];
                part[0] += hv * g[0]; part[1] += hv * g[1]; part[2] += hv * g[2];
                part[3] += hv * g[3]; part[4] += hv * g[4];
            }
            *(f16x4*)&h16[(size_t)b * D_IN + co * 100 + o0] = st;
        }
    }

    // ---- gate reduce: softmax, top-3 renormalized
    #pragma unroll
    for (int e = 0; e < 5; ++e) {
        float v = part[e];
        for (int off = 32; off > 0; off >>= 1) v += __shfl_down(v, off, 64);
        if (lane == 0) red[wv][e] = v;
    }
    __syncthreads();
    if (t == 0) {
        float lg[5], p[5];
        float mx = -1e30f;
        for (int e = 0; e < 5; ++e) {
            lg[e] = red[0][e] + red[1][e] + red[2][e] + red[3][e] + gb[e];
            mx = fmaxf(mx, lg[e]);
        }
        float sum = 0.f;
        for (int e = 0; e < 5; ++e) { p[e] = expf(lg[e] - mx); sum += p[e]; }
        for (int e = 0; e < 5; ++e) p[e] /= sum;
        bool used[5] = {false, false, false, false, false};
        float out5[5] = {0, 0, 0, 0, 0};
        int ti[3]; float tv[3]; float tsum = 0.f;
        for (int jj = 0; jj < 3; ++jj) {
            int best = 0; float bv = -1.f;
            for (int e = 0; e < 5; ++e)
                if (!used[e] && p[e] > bv) { bv = p[e]; best = e; }
            used[best] = true; ti[jj] = best; tv[jj] = bv; tsum += bv;
        }
        for (int jj = 0; jj < 3; ++jj) out5[ti[jj]] = tv[jj] / tsum;
        for (int e = 0; e < 5; ++e) wfull[b * 5 + e] = out5[e];
    }
}

// ---------------- kernel 2: fused expert pipeline.
union SLds {
    struct { _Float16 As[64 * 40]; _Float16 Bs[128 * 40]; } p1;  // e1 staging (pad 40)
    _Float16 e2ws[128 * 136];                                    // e2 weights (pad 136)
};

__global__ __launch_bounds__(256, 3) void k_e1e2(
    const _Float16* __restrict__ h16, const _Float16* __restrict__ wT,
    const _Float16* __restrict__ e2T,
    const float* __restrict__ e1b, const float* __restrict__ e2b,
    const float* __restrict__ wfull, float* __restrict__ moe)
{
    __shared__ SLds u;                                  // 34816 B
    __shared__ __align__(16) _Float16 h1s[64 * 136];    // 17408 B
    __shared__ float wf5[5 * 64];                       // 1280 B
    int m0 = blockIdx.x * 64;
    int e = blockIdx.y;
    int t = threadIdx.x;
    int lane = t & 63, wv = t >> 6;
    int waveM = wv >> 1, waveN = wv & 1;
    int quad = lane >> 4, l16 = lane & 15;

    for (int i = t; i < 320; i += 256)
        wf5[i] = wfull[(size_t)(m0 + (i & 63)) * 5 + (i >> 6)];

    const _Float16* wbase = wT + (size_t)e * D_H * D_IN;
    f32x4 acc[2][4];
    #pragma unroll
    for (int i = 0; i < 2; ++i)
        #pragma unroll
        for (int j = 0; j < 4; ++j) acc[i][j] = (f32x4){0.f, 0.f, 0.f, 0.f};

    int arow = t >> 2, acol = (t & 3) * 8;
    for (int k0 = 0; k0 < D_IN; k0 += 32) {
        *(uint4*)(&u.p1.As[arow * 40 + acol]) =
            *(const uint4*)(&h16[(size_t)(m0 + arow) * D_IN + k0 + acol]);
        *(uint4*)(&u.p1.Bs[arow * 40 + acol]) =
            *(const uint4*)(&wbase[(size_t)arow * D_IN + k0 + acol]);
        *(uint4*)(&u.p1.Bs[(arow + 64) * 40 + acol]) =
            *(const uint4*)(&wbase[(size_t)(arow + 64) * D_IN + k0 + acol]);
        __syncthreads();
        f16x8 a[2], bfr[4];
        #pragma unroll
        for (int ms = 0; ms < 2; ++ms)
            a[ms] = *(const f16x8*)(&u.p1.As[(waveM * 32 + ms * 16 + l16) * 40 + quad * 8]);
        #pragma unroll
        for (int ns = 0; ns < 4; ++ns)
            bfr[ns] = *(const f16x8*)(&u.p1.Bs[(waveN * 64 + ns * 16 + l16) * 40 + quad * 8]);
        #pragma unroll
        for (int ms = 0; ms < 2; ++ms)
            #pragma unroll
            for (int ns = 0; ns < 4; ++ns)
                acc[ms][ns] = __builtin_amdgcn_mfma_f32_16x16x32_f16(a[ms], bfr[ns], acc[ms][ns], 0, 0, 0);
        __syncthreads();
    }

    #pragma unroll
    for (int ms = 0; ms < 2; ++ms) {
        int rbase = waveM * 32 + ms * 16 + quad * 4;
        #pragma unroll
        for (int ns = 0; ns < 4; ++ns) {
            int n = waveN * 64 + ns * 16 + l16;
            float bias = e1b[e * D_H + n];
            #pragma unroll
            for (int r = 0; r < 4; ++r)
                h1s[(rbase + r) * 136 + n] = (_Float16)tanhf(acc[ms][ns][r] + bias);
        }
    }
    __syncthreads();

    {
        int r2 = t >> 1, c2 = (t & 1) * 64;
        const _Float16* src = e2T + (size_t)e * D_H * D_H + (size_t)r2 * D_H + c2;
        #pragma unroll
        for (int i = 0; i < 8; ++i)
            *(uint4*)(&u.e2ws[r2 * 136 + c2 + i * 8]) = *(const uint4*)(src + i * 8);
    }
    __syncthreads();

    f32x4 acc2[2][4];
    #pragma unroll
    for (int i = 0; i < 2; ++i)
        #pragma unroll
        for (int j = 0; j < 4; ++j) acc2[i][j] = (f32x4){0.f, 0.f, 0.f, 0.f};
    #pragma unroll
    for (int kc = 0; kc < 4; ++kc) {
        f16x8 a2[2], b2[4];
        #pragma unroll
        for (int ms = 0; ms < 2; ++ms)
            a2[ms] = *(const f16x8*)(&h1s[(waveM * 32 + ms * 16 + l16) * 136 + kc * 32 + quad * 8]);
        #pragma unroll
        for (int ns = 0; ns < 4; ++ns)
            b2[ns] = *(const f16x8*)(&u.e2ws[(waveN * 64 + ns * 16 + l16) * 136 + kc * 32 + quad * 8]);
        #pragma unroll
        for (int ms = 0; ms < 2; ++ms)
            #pragma unroll
            for (int ns = 0; ns < 4; ++ns)
                acc2[ms][ns] = __builtin_amdgcn_mfma_f32_16x16x32_f16(a2[ms], b2[ns], acc2[ms][ns], 0, 0, 0);
    }

    #pragma unroll
    for (int ms = 0; ms < 2; ++ms) {
        int rbase = waveM * 32 + ms * 16 + quad * 4;
        #pragma unroll
        for (int ns = 0; ns < 4; ++ns) {
            int n = waveN * 64 + ns * 16 + l16;
            float bias = e2b[e * D_H + n];
            #pragma unroll
            for (int r = 0; r < 4; ++r) {
                int row = rbase + r;
                float w = wf5[e * 64 + row];
                if (w != 0.f) {
                    float h2 = tanhf(acc2[ms][ns][r] + bias);
                    unsafeAtomicAdd(&moe[(size_t)(m0 + row) * D_H + n], w * h2);
                }
            }
        }
    }
}

// ---------------- kernel 3: head: logits = moe @ smw + smb, softmax -> out
__global__ __launch_bounds__(256) void k_head(
    const float* __restrict__ moe, const float* __restrict__ smw,
    const float* __restrict__ smb, float* __restrict__ out)
{
    __shared__ float moesT[128 * 66];
    __shared__ float smws[1280];
    __shared__ float smbs[16];
    __shared__ float lg[64 * 12];
    int b0 = blockIdx.x * 64;
    int t = threadIdx.x;
    for (int i = t; i < 1280; i += 256) smws[i] = smw[i];
    if (t < 10) smbs[t] = smb[t];
    {
        int row = t >> 2, cb = (t & 3) * 32;
        #pragma unroll
        for (int i = 0; i < 8; ++i) {
            float4 v = *(const float4*)&moe[(size_t)(b0 + row) * D_H + cb + i * 4];
            moesT[(cb + i * 4 + 0) * 66 + row] = v.x;
            moesT[(cb + i * 4 + 1) * 66 + row] = v.y;
            moesT[(cb + i * 4 + 2) * 66 + row] = v.z;
            moesT[(cb + i * 4 + 3) * 66 + row] = v.w;
        }
    }
    __syncthreads();
    {
        int row = t & 63, grp = t >> 6;
        int c0 = grp, c1 = grp + 4, c2 = grp + 8;
        float s0 = 0.f, s1 = 0.f, s2 = 0.f;
        for (int k = 0; k < 128; ++k) {
            float m = moesT[k * 66 + row];
            s0 += m * smws[k * 10 + c0];
            s1 += m * smws[k * 10 + c1];
            if (c2 < 10) s2 += m * smws[k * 10 + c2];
        }
        lg[row * 12 + c0] = s0 + smbs[c0];
        lg[row * 12 + c1] = s1 + smbs[c1];
        if (c2 < 10) lg[row * 12 + c2] = s2 + smbs[c2];
    }
    __syncthreads();
    if (t < 64) {
        float mx = -1e30f;
        for (int c = 0; c < 10; ++c) mx = fmaxf(mx, lg[t * 12 + c]);
        float s = 0.f, ex[10];
        for (int c = 0; c < 10; ++c) { ex[c] = expf(lg[t * 12 + c] - mx); s += ex[c]; }
        float inv = 1.f / s;
        for (int c = 0; c < 10; ++c) out[(size_t)(b0 + t) * 10 + c] = ex[c] * inv;
    }
}

extern "C" void kernel_launch(void* const* d_in, const int* in_sizes, int n_in,
                              void* d_out, int out_size, void* d_ws, size_t ws_size,
                              hipStream_t stream)
{
    const float* x   = (const float*)d_in[0];
    const float* c1w = (const float*)d_in[1];
    const float* c1b = (const float*)d_in[2];
    const float* c2w = (const float*)d_in[3];
    const float* c2b = (const float*)d_in[4];
    const float* gw  = (const float*)d_in[5];
    const float* gb  = (const float*)d_in[6];
    const float* e1w = (const float*)d_in[7];
    const float* e1b = (const float*)d_in[8];
    const float* e2w = (const float*)d_in[9];
    const float* e2b = (const float*)d_in[10];
    const float* smw = (const float*)d_in[11];
    const float* smb = (const float*)d_in[12];
    float* out = (float*)d_out;

    char* ws = (char*)d_ws;
    size_t off = 0;
    auto alloc = [&](size_t bytes) {
        void* p = ws + off;
        off += (bytes + 255) & ~(size_t)255;
        return p;
    };
    _Float16* h16 = (_Float16*)alloc((size_t)NB * D_IN * 2);          // 52.4 MB
    _Float16* wT  = (_Float16*)alloc((size_t)NE * D_H * D_IN * 2);    // 4.1 MB
    _Float16* e2T = (_Float16*)alloc((size_t)NE * D_H * D_H * 2);     // 0.16 MB
    float* wfull  = (float*)alloc((size_t)NB * NE * 4);               // 0.16 MB
    float* moe    = (float*)alloc((size_t)NB * D_H * 4);              // 4.2 MB

    hipMemsetAsync(moe, 0, (size_t)NB * D_H * 4, stream);
    k_wconv<<<dim3(NE, D_IN / 64, D_H / 64), 256, 0, stream>>>(e1w, wT);
    k_wprep2<<<dim3(NE, 2, 2), 256, 0, stream>>>(e2w, e2T);
    k_feat<<<dim3(NB), 256, 0, stream>>>(x, c1w, c1b, c2w, c2b, gw, gb, h16, wfull);
    k_e1e2<<<dim3(NB / 64, NE), 256, 0, stream>>>(h16, wT, e2T, e1b, e2b, wfull, moe);
    k_head<<<dim3(NB / 64), 256, 0, stream>>>(moe, smw, smb, out);
}

// Round 5
// 341.102 us; speedup vs baseline: 3.7287x; 1.0435x over previous
//
#include <hip/hip_runtime.h>
#include <hip/hip_bf16.h>
#include <hip/hip_fp16.h>

#define NB 8192
#define D_IN 3200
#define D_H 128
#define NE 5

typedef _Float16 f16x8 __attribute__((ext_vector_type(8)));
typedef _Float16 f16x4 __attribute__((ext_vector_type(4)));
typedef float f32x4 __attribute__((ext_vector_type(4)));

// async global->LDS, 16B per lane; lds base must be wave-uniform, lanes land at base+lane*16
__device__ __forceinline__ void gload16(const _Float16* g, _Float16* l) {
    __builtin_amdgcn_global_load_lds(
        (const __attribute__((address_space(1))) void*)g,
        (__attribute__((address_space(3))) void*)l, 16, 0, 0);
}

// ---------------- kernel 0: e1_w [5][3200][128] f32 -> f16 transposed [5][128][3200]
__global__ __launch_bounds__(256) void k_wconv(const float* __restrict__ e1w,
                                               _Float16* __restrict__ wT) {
    __shared__ float tile[64][65];
    int e = blockIdx.x;
    int k0 = blockIdx.y * 64;
    int n0 = blockIdx.z * 64;
    const float* src = e1w + (size_t)e * D_IN * D_H;
    _Float16* dst = wT + (size_t)e * D_H * D_IN;
    int t = threadIdx.x;
    for (int i = 0; i < 16; ++i) {
        int idx = t + i * 256;
        int kr = idx >> 6, nc = idx & 63;
        tile[kr][nc] = src[(size_t)(k0 + kr) * D_H + n0 + nc];
    }
    __syncthreads();
    for (int i = 0; i < 16; ++i) {
        int idx = t + i * 256;
        int nr = idx >> 6, kc = idx & 63;
        dst[(size_t)(n0 + nr) * D_IN + k0 + kc] = (_Float16)tile[kc][nr];
    }
}

// ---------------- kernel 0b: e2_w [5][128][128] f32 -> f16 transposed (n,k)
__global__ __launch_bounds__(256) void k_wprep2(const float* __restrict__ e2w,
                                                _Float16* __restrict__ e2T) {
    __shared__ float tile[64][65];
    int e = blockIdx.x;
    int k0 = blockIdx.y * 64;
    int n0 = blockIdx.z * 64;
    const float* src = e2w + (size_t)e * D_H * D_H;
    _Float16* dst = e2T + (size_t)e * D_H * D_H;
    int t = threadIdx.x;
    for (int i = 0; i < 16; ++i) {
        int idx = t + i * 256;
        int kr = idx >> 6, nc = idx & 63;
        tile[kr][nc] = src[(size_t)(k0 + kr) * D_H + n0 + nc];
    }
    __syncthreads();
    for (int i = 0; i < 16; ++i) {
        int idx = t + i * 256;
        int nr = idx >> 6, kc = idx & 63;
        dst[(size_t)(n0 + nr) * D_H + k0 + kc] = (_Float16)tile[kc][nr];
    }
}

// ---------------- kernel 0c: gw [3200][5] -> gwC [5][100(o)][32(co)] for coalesced epilogue loads
__global__ __launch_bounds__(256) void k_wgate(const float* __restrict__ gw,
                                               float* __restrict__ gwC) {
    int i = blockIdx.x * 256 + threadIdx.x;
    if (i < 16000) {
        int e = i / 3200, rem = i - e * 3200;
        int o = rem >> 5, co = rem & 31;
        gwC[i] = gw[(co * 100 + o) * 5 + e];
    }
}

// ---------------- kernel 1: conv1+pool (VALU) -> conv2 shifted-GEMM MFMA -> h16 + gate
#define PCL_S 24
__global__ __launch_bounds__(256, 3) void k_feat(
    const float* __restrict__ x, const float* __restrict__ c1w, const float* __restrict__ c1b,
    const float* __restrict__ c2w, const float* __restrict__ c2b,
    const float* __restrict__ gwC, const float* __restrict__ gb,
    _Float16* __restrict__ h16, float* __restrict__ wfull)
{
    __shared__ __align__(16) float xs[784];
    __shared__ __align__(16) float c1wsP[16 * 28];
    __shared__ __align__(16) _Float16 b2h[32 * 160];
    __shared__ __align__(16) _Float16 b2l[32 * 160];
    __shared__ __align__(16) _Float16 pclh[144 * PCL_S];
    __shared__ __align__(16) _Float16 pcll[144 * PCL_S];
    __shared__ float red[4][8];
    int b = blockIdx.x;
    int t = threadIdx.x;

    for (int i = t; i < 784; i += 256) xs[i] = x[(size_t)b * 784 + i];
    for (int i = t; i < 400; i += 256) {
        int c = i / 25, q = i - c * 25;
        c1wsP[c * 28 + q] = c1w[i];
    }
    for (int i = t; i < 5120; i += 256) {
        int co = i / 160, k = i - co * 160;
        int s = k >> 4, ci = k & 15;
        float v = (s == 9) ? 0.f : c2w[(co * 16 + ci) * 9 + s];
        _Float16 vh = (_Float16)v;
        b2h[i] = vh;
        b2l[i] = (_Float16)(v - (float)vh);
    }
    __syncthreads();

    // ---- conv1 + 2x2 maxpool -> pcl channel-last (hi/lo f16)
    {
        int c = t >> 4;
        int tile = t & 15;
        int tr = tile >> 2, tc = tile & 3;
        float w1r[25];
        #pragma unroll
        for (int q = 0; q < 6; ++q) {
            float4 v4 = *(const float4*)&c1wsP[c * 28 + q * 4];
            w1r[q * 4 + 0] = v4.x; w1r[q * 4 + 1] = v4.y;
            w1r[q * 4 + 2] = v4.z; w1r[q * 4 + 3] = v4.w;
        }
        w1r[24] = c1wsP[c * 28 + 24];
        float bias1 = c1b[c];
        float win[5][10];
        float pacc[3][3];
        #pragma unroll
        for (int i = 0; i < 3; ++i)
            #pragma unroll
            for (int j = 0; j < 3; ++j) pacc[i][j] = 0.f;
        int r0 = 6 * tr, col0 = 6 * tc;
        #pragma unroll
        for (int cr = 0; cr < 6; ++cr) {
            if (cr == 0) {
                #pragma unroll
                for (int rr = 0; rr < 5; ++rr)
                    #pragma unroll
                    for (int m = 0; m < 5; ++m) {
                        float2 v = *(const float2*)&xs[(r0 + rr) * 28 + col0 + 2 * m];
                        win[rr][2 * m] = v.x; win[rr][2 * m + 1] = v.y;
                    }
            } else {
                int dstr = (cr + 4) % 5;
                #pragma unroll
                for (int m = 0; m < 5; ++m) {
                    float2 v = *(const float2*)&xs[(r0 + cr + 4) * 28 + col0 + 2 * m];
                    win[dstr][2 * m] = v.x; win[dstr][2 * m + 1] = v.y;
                }
            }
            #pragma unroll
            for (int oc = 0; oc < 6; ++oc) {
                float s = bias1;
                #pragma unroll
                for (int u = 0; u < 5; ++u)
                    #pragma unroll
                    for (int v = 0; v < 5; ++v)
                        s += win[(cr + u) % 5][oc + v] * w1r[u * 5 + v];
                s = fmaxf(s, 0.f);
                pacc[cr >> 1][oc >> 1] = fmaxf(pacc[cr >> 1][oc >> 1], s);
            }
        }
        #pragma unroll
        for (int i = 0; i < 3; ++i)
            #pragma unroll
            for (int j = 0; j < 3; ++j) {
                int pos = (3 * tr + i) * 12 + (3 * tc + j);
                float v = pacc[i][j];
                _Float16 vh = (_Float16)v;
                pclh[pos * PCL_S + c] = vh;
                pcll[pos * PCL_S + c] = (_Float16)(v - (float)vh);
            }
    }
    __syncthreads();

    // ---- conv2 MFMA: wave handles fixed nt (B frags cached in regs), mt strided
    float part[5] = {0, 0, 0, 0, 0};
    int lane = t & 63, wv = t >> 6;
    int quad = lane >> 4, l16 = lane & 15;
    int quadh = quad >> 1, quadl = quad & 1;
    const int offA[5] = {0, 2, 13, 24, 26};   // shifts s=0,2,4,6,8
    const int offB[5] = {1, 12, 14, 25, 0};   // shifts s=1,3,5,7,9 (9 dummy)
    {
        int nt = wv & 1;
        int co = nt * 16 + l16;
        f16x8 bh[5], bl[5];
        #pragma unroll
        for (int kc = 0; kc < 5; ++kc) {
            bh[kc] = *(const f16x8*)&b2h[co * 160 + kc * 32 + quad * 8];
            bl[kc] = *(const f16x8*)&b2l[co * 160 + kc * 32 + quad * 8];
        }
        float bco = c2b[co];
        for (int mt = wv >> 1; mt < 7; mt += 2) {
            int o_a = mt * 16 + l16;
            int o_cl = o_a < 100 ? o_a : 99;
            int pb = (o_cl / 10) * 12 + (o_cl % 10);
            f32x4 acc = (f32x4){0.f, 0.f, 0.f, 0.f};
            #pragma unroll
            for (int kc = 0; kc < 5; ++kc) {
                int off = quadh ? offB[kc] : offA[kc];
                f16x8 ah = *(const f16x8*)&pclh[(pb + off) * PCL_S + quadl * 8];
                f16x8 al = *(const f16x8*)&pcll[(pb + off) * PCL_S + quadl * 8];
                acc = __builtin_amdgcn_mfma_f32_16x16x32_f16(ah, bh[kc], acc, 0, 0, 0);
                acc = __builtin_amdgcn_mfma_f32_16x16x32_f16(ah, bl[kc], acc, 0, 0, 0);
                acc = __builtin_amdgcn_mfma_f32_16x16x32_f16(al, bh[kc], acc, 0, 0, 0);
            }
            if (mt < 6 || quad == 0) {
                int o0 = mt * 16 + quad * 4;
                f16x4 st;
                #pragma unroll
                for (int r = 0; r < 4; ++r) {
                    float hv = fmaxf(acc[r] + bco, 0.f);
                    st[r] = (_Float16)hv;
                    #pragma unroll
                    for (int e = 0; e < 5; ++e)
                        part[e] += hv * gwC[e * 3200 + (o0 + r) * 32 + co];
                }
                *(f16x4*)&h16[(size_t)b * D_IN + co * 100 + o0] = st;
            }
        }
    }

    // ---- gate reduce: softmax, top-3 renormalized
    #pragma unroll
    for (int e = 0; e < 5; ++e) {
        float v = part[e];
        for (int off = 32; off > 0; off >>= 1) v += __shfl_down(v, off, 64);
        if (lane == 0) red[wv][e] = v;
    }
    __syncthreads();
    if (t == 0) {
        float lg[5], p[5];
        float mx = -1e30f;
        for (int e = 0; e < 5; ++e) {
            lg[e] = red[0][e] + red[1][e] + red[2][e] + red[3][e] + gb[e];
            mx = fmaxf(mx, lg[e]);
        }
        float sum = 0.f;
        for (int e = 0; e < 5; ++e) { p[e] = expf(lg[e] - mx); sum += p[e]; }
        for (int e = 0; e < 5; ++e) p[e] /= sum;
        bool used[5] = {false, false, false, false, false};
        float out5[5] = {0, 0, 0, 0, 0};
        int ti[3]; float tv[3]; float tsum = 0.f;
        for (int jj = 0; jj < 3; ++jj) {
            int best = 0; float bv = -1.f;
            for (int e = 0; e < 5; ++e)
                if (!used[e] && p[e] > bv) { bv = p[e]; best = e; }
            used[best] = true; ti[jj] = best; tv[jj] = bv; tsum += bv;
        }
        for (int jj = 0; jj < 3; ++jj) out5[ti[jj]] = tv[jj] / tsum;
        for (int e = 0; e < 5; ++e) wfull[b * 5 + e] = out5[e];
    }
}

// ---------------- kernel 2: fused experts, 128x128 M-tile, global_load_lds staging.
// grid (64 mtiles, 5 experts); 4 waves each 64x64 (4x4 of 16x16x32 MFMA).
#define H1S 136   // h1s/e2ws row stride in halves (272B, 16B-aligned)
__global__ __launch_bounds__(256, 2) void k_e1e2(
    const _Float16* __restrict__ h16, const _Float16* __restrict__ wT,
    const _Float16* __restrict__ e2T,
    const float* __restrict__ e1b, const float* __restrict__ e2b,
    const float* __restrict__ wfull, float* __restrict__ moe)
{
    __shared__ __align__(16) _Float16 stage[128 * H1S]; // K-loop: As=stage[0..4095], Bs=[4096..8191]; later e2ws
    __shared__ __align__(16) _Float16 h1s[128 * H1S];
    __shared__ float wfl[128];
    int m0 = blockIdx.x * 128;
    int e = blockIdx.y;
    int t = threadIdx.x;
    int lane = t & 63, wv = t >> 6;
    int waveM = wv >> 1, waveN = wv & 1;
    int quad = lane >> 4, l16 = lane & 15;
    if (t < 128) wfl[t] = wfull[(size_t)(m0 + t) * 5 + e];

    _Float16* As = stage;            // [128][32] contiguous (global_load_lds: no padding)
    _Float16* Bs = stage + 4096;
    const _Float16* abase = h16 + (size_t)m0 * D_IN;
    const _Float16* bbase = wT + (size_t)e * (D_H * D_IN);
    int srow = t >> 2;               // 0..63
    int scol = (t & 3) * 8;
    f32x4 acc[4][4];
    #pragma unroll
    for (int i = 0; i < 4; ++i)
        #pragma unroll
        for (int j = 0; j < 4; ++j) acc[i][j] = (f32x4){0.f, 0.f, 0.f, 0.f};

    for (int k0 = 0; k0 < D_IN; k0 += 32) {
        gload16(abase + (size_t)srow * D_IN + k0 + scol,        As + wv * 512);
        gload16(abase + (size_t)(64 + srow) * D_IN + k0 + scol, As + 2048 + wv * 512);
        gload16(bbase + (size_t)srow * D_IN + k0 + scol,        Bs + wv * 512);
        gload16(bbase + (size_t)(64 + srow) * D_IN + k0 + scol, Bs + 2048 + wv * 512);
        __syncthreads();   // drains vmcnt incl. async LDS stores
        f16x8 af[4], bf[4];
        #pragma unroll
        for (int ms = 0; ms < 4; ++ms)
            af[ms] = *(const f16x8*)&As[(waveM * 64 + ms * 16 + l16) * 32 + quad * 8];
        #pragma unroll
        for (int ns = 0; ns < 4; ++ns)
            bf[ns] = *(const f16x8*)&Bs[(waveN * 64 + ns * 16 + l16) * 32 + quad * 8];
        #pragma unroll
        for (int ms = 0; ms < 4; ++ms)
            #pragma unroll
            for (int ns = 0; ns < 4; ++ns)
                acc[ms][ns] = __builtin_amdgcn_mfma_f32_16x16x32_f16(af[ms], bf[ns], acc[ms][ns], 0, 0, 0);
        __syncthreads();
    }

    // h1 = tanh(acc + b1) -> h1s (C/D: row=quad*4+r within 16-tile, col=l16)
    #pragma unroll
    for (int ms = 0; ms < 4; ++ms) {
        int rbase = waveM * 64 + ms * 16 + quad * 4;
        #pragma unroll
        for (int ns = 0; ns < 4; ++ns) {
            int n = waveN * 64 + ns * 16 + l16;
            float bias = e1b[e * D_H + n];
            #pragma unroll
            for (int r = 0; r < 4; ++r)
                h1s[(rbase + r) * H1S + n] = (_Float16)tanhf(acc[ms][ns][r] + bias);
        }
    }
    __syncthreads();   // h1s visible; stage (As/Bs) dead -> reuse as e2ws

    _Float16* e2ws = stage;          // [128][H1S]
    {
        int rr = t >> 1, cc = (t & 1) * 64;
        const _Float16* src = e2T + (size_t)e * (D_H * D_H) + (size_t)rr * D_H + cc;
        #pragma unroll
        for (int i = 0; i < 8; ++i)
            *(uint4*)&e2ws[rr * H1S + cc + i * 8] = *(const uint4*)(src + i * 8);
    }
    __syncthreads();

    f32x4 acc2[4][4];
    #pragma unroll
    for (int i = 0; i < 4; ++i)
        #pragma unroll
        for (int j = 0; j < 4; ++j) acc2[i][j] = (f32x4){0.f, 0.f, 0.f, 0.f};
    #pragma unroll
    for (int kc = 0; kc < 4; ++kc) {
        f16x8 a2[4], b2[4];
        #pragma unroll
        for (int ms = 0; ms < 4; ++ms)
            a2[ms] = *(const f16x8*)&h1s[(waveM * 64 + ms * 16 + l16) * H1S + kc * 32 + quad * 8];
        #pragma unroll
        for (int ns = 0; ns < 4; ++ns)
            b2[ns] = *(const f16x8*)&e2ws[(waveN * 64 + ns * 16 + l16) * H1S + kc * 32 + quad * 8];
        #pragma unroll
        for (int ms = 0; ms < 4; ++ms)
            #pragma unroll
            for (int ns = 0; ns < 4; ++ns)
                acc2[ms][ns] = __builtin_amdgcn_mfma_f32_16x16x32_f16(a2[ms], b2[ns], acc2[ms][ns], 0, 0, 0);
    }

    #pragma unroll
    for (int ms = 0; ms < 4; ++ms) {
        int rbase = waveM * 64 + ms * 16 + quad * 4;
        #pragma unroll
        for (int ns = 0; ns < 4; ++ns) {
            int n = waveN * 64 + ns * 16 + l16;
            float bias = e2b[e * D_H + n];
            #pragma unroll
            for (int r = 0; r < 4; ++r) {
                int row = rbase + r;
                float w = wfl[row];
                if (w != 0.f) {
                    float h2 = tanhf(acc2[ms][ns][r] + bias);
                    unsafeAtomicAdd(&moe[(size_t)(m0 + row) * D_H + n], w * h2);
                }
            }
        }
    }
}

// ---------------- kernel 3: head: logits = moe @ smw + smb, softmax -> out
__global__ __launch_bounds__(256) void k_head(
    const float* __restrict__ moe, const float* __restrict__ smw,
    const float* __restrict__ smb, float* __restrict__ out)
{
    __shared__ float moesT[128 * 66];
    __shared__ float smws[1280];
    __shared__ float smbs[16];
    __shared__ float lg[64 * 12];
    int b0 = blockIdx.x * 64;
    int t = threadIdx.x;
    for (int i = t; i < 1280; i += 256) smws[i] = smw[i];
    if (t < 10) smbs[t] = smb[t];
    {
        int row = t >> 2, cb = (t & 3) * 32;
        #pragma unroll
        for (int i = 0; i < 8; ++i) {
            float4 v = *(const float4*)&moe[(size_t)(b0 + row) * D_H + cb + i * 4];
            moesT[(cb + i * 4 + 0) * 66 + row] = v.x;
            moesT[(cb + i * 4 + 1) * 66 + row] = v.y;
            moesT[(cb + i * 4 + 2) * 66 + row] = v.z;
            moesT[(cb + i * 4 + 3) * 66 + row] = v.w;
        }
    }
    __syncthreads();
    {
        int row = t & 63, grp = t >> 6;
        int c0 = grp, c1 = grp + 4, c2 = grp + 8;
        float s0 = 0.f, s1 = 0.f, s2 = 0.f;
        for (int k = 0; k < 128; ++k) {
            float m = moesT[k * 66 + row];
            s0 += m * smws[k * 10 + c0];
            s1 += m * smws[k * 10 + c1];
            if (c2 < 10) s2 += m * smws[k * 10 + c2];
        }
        lg[row * 12 + c0] = s0 + smbs[c0];
        lg[row * 12 + c1] = s1 + smbs[c1];
        if (c2 < 10) lg[row * 12 + c2] = s2 + smbs[c2];
    }
    __syncthreads();
    if (t < 64) {
        float mx = -1e30f;
        for (int c = 0; c < 10; ++c) mx = fmaxf(mx, lg[t * 12 + c]);
        float s = 0.f, ex[10];
        for (int c = 0; c < 10; ++c) { ex[c] = expf(lg[t * 12 + c] - mx); s += ex[c]; }
        float inv = 1.f / s;
        for (int c = 0; c < 10; ++c) out[(size_t)(b0 + t) * 10 + c] = ex[c] * inv;
    }
}

extern "C" void kernel_launch(void* const* d_in, const int* in_sizes, int n_in,
                              void* d_out, int out_size, void* d_ws, size_t ws_size,
                              hipStream_t stream)
{
    const float* x   = (const float*)d_in[0];
    const float* c1w = (const float*)d_in[1];
    const float* c1b = (const float*)d_in[2];
    const float* c2w = (const float*)d_in[3];
    const float* c2b = (const float*)d_in[4];
    const float* gw  = (const float*)d_in[5];
    const float* gb  = (const float*)d_in[6];
    const float* e1w = (const float*)d_in[7];
    const float* e1b = (const float*)d_in[8];
    const float* e2w = (const float*)d_in[9];
    const float* e2b = (const float*)d_in[10];
    const float* smw = (const float*)d_in[11];
    const float* smb = (const float*)d_in[12];
    float* out = (float*)d_out;

    char* ws = (char*)d_ws;
    size_t off = 0;
    auto alloc = [&](size_t bytes) {
        void* p = ws + off;
        off += (bytes + 255) & ~(size_t)255;
        return p;
    };
    _Float16* h16 = (_Float16*)alloc((size_t)NB * D_IN * 2);          // 52.4 MB
    _Float16* wT  = (_Float16*)alloc((size_t)NE * D_H * D_IN * 2);    // 4.1 MB
    _Float16* e2T = (_Float16*)alloc((size_t)NE * D_H * D_H * 2);     // 0.16 MB
    float* wfull  = (float*)alloc((size_t)NB * NE * 4);               // 0.16 MB
    float* moe    = (float*)alloc((size_t)NB * D_H * 4);              // 4.2 MB
    float* gwC    = (float*)alloc((size_t)NE * D_IN * 4);             // 64 KB

    hipMemsetAsync(moe, 0, (size_t)NB * D_H * 4, stream);
    k_wconv<<<dim3(NE, D_IN / 64, D_H / 64), 256, 0, stream>>>(e1w, wT);
    k_wprep2<<<dim3(NE, 2, 2), 256, 0, stream>>>(e2w, e2T);
    k_wgate<<<dim3(63), 256, 0, stream>>>(gw, gwC);
    k_feat<<<dim3(NB), 256, 0, stream>>>(x, c1w, c1b, c2w, c2b, gwC, gb, h16, wfull);
    k_e1e2<<<dim3(NB / 128, NE), 256, 0, stream>>>(h16, wT, e2T, e1b, e2b, wfull, moe);
    k_head<<<dim3(NB / 64), 256, 0, stream>>>(moe, smw, smb, out);
}

// Round 6
// 339.160 us; speedup vs baseline: 3.7500x; 1.0057x over previous
//
#include <hip/hip_runtime.h>
#include <hip/hip_bf16.h>
#include <hip/hip_fp16.h>

#define NB 8192
#define D_IN 3200
#define D_H 128
#define NE 5

typedef _Float16 f16x8 __attribute__((ext_vector_type(8)));
typedef _Float16 f16x4 __attribute__((ext_vector_type(4)));
typedef float f32x4 __attribute__((ext_vector_type(4)));

// async global->LDS, 16B per lane; lds base wave-uniform, lanes land at base+lane*16
__device__ __forceinline__ void gload16(const _Float16* g, _Float16* l) {
    __builtin_amdgcn_global_load_lds(
        (const __attribute__((address_space(1))) void*)g,
        (__attribute__((address_space(3))) void*)l, 16, 0, 0);
}

// ---------------- kernel 0: e1_w [5][3200][128] f32 -> f16 transposed [5][128][3200]
__global__ __launch_bounds__(256) void k_wconv(const float* __restrict__ e1w,
                                               _Float16* __restrict__ wT) {
    __shared__ float tile[64][65];
    int e = blockIdx.x;
    int k0 = blockIdx.y * 64;
    int n0 = blockIdx.z * 64;
    const float* src = e1w + (size_t)e * D_IN * D_H;
    _Float16* dst = wT + (size_t)e * D_H * D_IN;
    int t = threadIdx.x;
    for (int i = 0; i < 16; ++i) {
        int idx = t + i * 256;
        int kr = idx >> 6, nc = idx & 63;
        tile[kr][nc] = src[(size_t)(k0 + kr) * D_H + n0 + nc];
    }
    __syncthreads();
    for (int i = 0; i < 16; ++i) {
        int idx = t + i * 256;
        int nr = idx >> 6, kc = idx & 63;
        dst[(size_t)(n0 + nr) * D_IN + k0 + kc] = (_Float16)tile[kc][nr];
    }
}

// ---------------- kernel 0b: e2_w [5][128][128] f32 -> f16 transposed (n,k)
__global__ __launch_bounds__(256) void k_wprep2(const float* __restrict__ e2w,
                                                _Float16* __restrict__ e2T) {
    __shared__ float tile[64][65];
    int e = blockIdx.x;
    int k0 = blockIdx.y * 64;
    int n0 = blockIdx.z * 64;
    const float* src = e2w + (size_t)e * D_H * D_H;
    _Float16* dst = e2T + (size_t)e * D_H * D_H;
    int t = threadIdx.x;
    for (int i = 0; i < 16; ++i) {
        int idx = t + i * 256;
        int kr = idx >> 6, nc = idx & 63;
        tile[kr][nc] = src[(size_t)(k0 + kr) * D_H + n0 + nc];
    }
    __syncthreads();
    for (int i = 0; i < 16; ++i) {
        int idx = t + i * 256;
        int nr = idx >> 6, kc = idx & 63;
        dst[(size_t)(n0 + nr) * D_H + k0 + kc] = (_Float16)tile[kc][nr];
    }
}

// ---------------- kernel 0c: gw [3200][5] -> gwC [5][100(o)][32(co)]
__global__ __launch_bounds__(256) void k_wgate(const float* __restrict__ gw,
                                               float* __restrict__ gwC) {
    int i = blockIdx.x * 256 + threadIdx.x;
    if (i < 16000) {
        int e = i / 3200, rem = i - e * 3200;
        int o = rem >> 5, co = rem & 31;
        gwC[i] = gw[(co * 100 + o) * 5 + e];
    }
}

// ---------------- kernel 1: conv1+pool (regs, window from GLOBAL) -> conv2 MFMA -> h16 + gate
#define PCL_S 24
__global__ __launch_bounds__(256, 3) void k_feat(
    const float* __restrict__ x, const float* __restrict__ c1w, const float* __restrict__ c1b,
    const float* __restrict__ c2w, const float* __restrict__ c2b,
    const float* __restrict__ gwC, const float* __restrict__ gb,
    _Float16* __restrict__ h16, float* __restrict__ wfull)
{
    __shared__ __align__(16) _Float16 b2h[32 * 160];     // [co][s*16+ci] hi
    __shared__ __align__(16) _Float16 b2l[32 * 160];     // lo
    __shared__ __align__(16) _Float16 pclh[144 * PCL_S]; // [pos][ci] hi
    __shared__ __align__(16) _Float16 pcll[144 * PCL_S]; // lo
    __shared__ float red[4][8];
    int b = blockIdx.x;
    int t = threadIdx.x;

    // ---- stage conv2 weights hi/lo (shift-only indexing, no div)
    {
        int co = t & 31, g = t >> 5;         // 8 groups x 20 k
        #pragma unroll 4
        for (int j = 0; j < 20; ++j) {
            int k = g * 20 + j;
            int s = k >> 4, ci = k & 15;
            float v = (s == 9) ? 0.f : c2w[(co * 16 + ci) * 9 + s];
            _Float16 vh = (_Float16)v;
            b2h[co * 160 + k] = vh;
            b2l[co * 160 + k] = (_Float16)(v - (float)vh);
        }
    }

    // ---- conv1 (5x5 valid, relu) + 2x2 maxpool; window read from GLOBAL into regs
    {
        int c = t >> 4;
        int tile = t & 15;
        int tr = tile >> 2, tc = tile & 3;   // 3x3 pooled tile origin
        float w1r[25];
        #pragma unroll
        for (int q = 0; q < 25; ++q) w1r[q] = c1w[c * 25 + q];
        float bias1 = c1b[c];
        const float* xb = x + (size_t)b * 784;
        float win[5][10];
        float pacc[3][3];
        #pragma unroll
        for (int i = 0; i < 3; ++i)
            #pragma unroll
            for (int j = 0; j < 3; ++j) pacc[i][j] = 0.f;
        int r0 = 6 * tr, col0 = 6 * tc;
        #pragma unroll
        for (int cr = 0; cr < 6; ++cr) {
            if (cr == 0) {
                #pragma unroll
                for (int rr = 0; rr < 5; ++rr)
                    #pragma unroll
                    for (int m = 0; m < 5; ++m) {
                        float2 v = *(const float2*)&xb[(r0 + rr) * 28 + col0 + 2 * m];
                        win[rr][2 * m] = v.x; win[rr][2 * m + 1] = v.y;
                    }
            } else {
                int dstr = (cr + 4) % 5;
                #pragma unroll
                for (int m = 0; m < 5; ++m) {
                    float2 v = *(const float2*)&xb[(r0 + cr + 4) * 28 + col0 + 2 * m];
                    win[dstr][2 * m] = v.x; win[dstr][2 * m + 1] = v.y;
                }
            }
            #pragma unroll
            for (int oc = 0; oc < 6; ++oc) {
                float s = bias1;
                #pragma unroll
                for (int u = 0; u < 5; ++u)
                    #pragma unroll
                    for (int v = 0; v < 5; ++v)
                        s += win[(cr + u) % 5][oc + v] * w1r[u * 5 + v];
                s = fmaxf(s, 0.f);
                pacc[cr >> 1][oc >> 1] = fmaxf(pacc[cr >> 1][oc >> 1], s);
            }
        }
        #pragma unroll
        for (int i = 0; i < 3; ++i)
            #pragma unroll
            for (int j = 0; j < 3; ++j) {
                int pos = (3 * tr + i) * 12 + (3 * tc + j);
                float v = pacc[i][j];
                _Float16 vh = (_Float16)v;
                pclh[pos * PCL_S + c] = vh;
                pcll[pos * PCL_S + c] = (_Float16)(v - (float)vh);
            }
    }
    __syncthreads();

    // ---- conv2 MFMA: wave handles fixed nt (B frags in regs), mt strided
    float part[5] = {0, 0, 0, 0, 0};
    int lane = t & 63, wv = t >> 6;
    int quad = lane >> 4, l16 = lane & 15;
    int quadh = quad >> 1, quadl = quad & 1;
    const int offA[5] = {0, 2, 13, 24, 26};   // shifts s=0,2,4,6,8
    const int offB[5] = {1, 12, 14, 25, 0};   // shifts s=1,3,5,7,9 (9 dummy)
    {
        int nt = wv & 1;
        int co = nt * 16 + l16;
        f16x8 bh[5], bl[5];
        #pragma unroll
        for (int kc = 0; kc < 5; ++kc) {
            bh[kc] = *(const f16x8*)&b2h[co * 160 + kc * 32 + quad * 8];
            bl[kc] = *(const f16x8*)&b2l[co * 160 + kc * 32 + quad * 8];
        }
        float bco = c2b[co];
        for (int mt = wv >> 1; mt < 7; mt += 2) {
            int o_a = mt * 16 + l16;
            int o_cl = o_a < 100 ? o_a : 99;
            int pb = (o_cl / 10) * 12 + (o_cl % 10);
            f32x4 acc = (f32x4){0.f, 0.f, 0.f, 0.f};
            #pragma unroll
            for (int kc = 0; kc < 5; ++kc) {
                int off = quadh ? offB[kc] : offA[kc];
                f16x8 ah = *(const f16x8*)&pclh[(pb + off) * PCL_S + quadl * 8];
                f16x8 al = *(const f16x8*)&pcll[(pb + off) * PCL_S + quadl * 8];
                acc = __builtin_amdgcn_mfma_f32_16x16x32_f16(ah, bh[kc], acc, 0, 0, 0);
                acc = __builtin_amdgcn_mfma_f32_16x16x32_f16(ah, bl[kc], acc, 0, 0, 0);
                acc = __builtin_amdgcn_mfma_f32_16x16x32_f16(al, bh[kc], acc, 0, 0, 0);
            }
            if (mt < 6 || quad == 0) {
                int o0 = mt * 16 + quad * 4;
                f16x4 st;
                #pragma unroll
                for (int r = 0; r < 4; ++r) {
                    float hv = fmaxf(acc[r] + bco, 0.f);
                    st[r] = (_Float16)hv;
                    #pragma unroll
                    for (int e = 0; e < 5; ++e)
                        part[e] += hv * gwC[e * 3200 + (o0 + r) * 32 + co];
                }
                *(f16x4*)&h16[(size_t)b * D_IN + co * 100 + o0] = st;
            }
        }
    }

    // ---- gate reduce: softmax, top-3 renormalized
    #pragma unroll
    for (int e = 0; e < 5; ++e) {
        float v = part[e];
        for (int off = 32; off > 0; off >>= 1) v += __shfl_down(v, off, 64);
        if (lane == 0) red[wv][e] = v;
    }
    __syncthreads();
    if (t == 0) {
        float lg[5], p[5];
        float mx = -1e30f;
        for (int e = 0; e < 5; ++e) {
            lg[e] = red[0][e] + red[1][e] + red[2][e] + red[3][e] + gb[e];
            mx = fmaxf(mx, lg[e]);
        }
        float sum = 0.f;
        for (int e = 0; e < 5; ++e) { p[e] = expf(lg[e] - mx); sum += p[e]; }
        for (int e = 0; e < 5; ++e) p[e] /= sum;
        bool used[5] = {false, false, false, false, false};
        float out5[5] = {0, 0, 0, 0, 0};
        int ti[3]; float tv[3]; float tsum = 0.f;
        for (int jj = 0; jj < 3; ++jj) {
            int best = 0; float bv = -1.f;
            for (int e = 0; e < 5; ++e)
                if (!used[e] && p[e] > bv) { bv = p[e]; best = e; }
            used[best] = true; ti[jj] = best; tv[jj] = bv; tsum += bv;
        }
        for (int jj = 0; jj < 3; ++jj) out5[ti[jj]] = tv[jj] / tsum;
        for (int e = 0; e < 5; ++e) wfull[b * 5 + e] = out5[e];
    }
}

// ---------------- kernel 2: fused experts, 64-row M-tile (grid 128x5 = 640 blocks,
// 3 blocks/CU), global_load_lds staging. 4 waves each 32x64 (2x4 of 16x16x32).
#define H1S 136
union SLds {
    struct { _Float16 As[64 * 32]; _Float16 Bs[128 * 32]; } p1;  // e1 staging (unpadded)
    _Float16 e2ws[128 * H1S];                                    // e2 weights (padded)
};

__global__ __launch_bounds__(256, 3) void k_e1e2(
    const _Float16* __restrict__ h16, const _Float16* __restrict__ wT,
    const _Float16* __restrict__ e2T,
    const float* __restrict__ e1b, const float* __restrict__ e2b,
    const float* __restrict__ wfull, float* __restrict__ moe)
{
    __shared__ SLds u;                                   // 34816 B
    __shared__ __align__(16) _Float16 h1s[64 * H1S];     // 17408 B
    __shared__ float wfl[64];
    int m0 = blockIdx.x * 64;
    int e = blockIdx.y;
    int t = threadIdx.x;
    int lane = t & 63, wv = t >> 6;
    int waveM = wv >> 1, waveN = wv & 1;
    int quad = lane >> 4, l16 = lane & 15;
    if (t < 64) wfl[t] = wfull[(size_t)(m0 + t) * 5 + e];

    const _Float16* abase = h16 + (size_t)m0 * D_IN;
    const _Float16* bbase = wT + (size_t)e * (D_H * D_IN);
    int srow = t >> 2;               // 0..63
    int scol = (t & 3) * 8;
    f32x4 acc[2][4];
    #pragma unroll
    for (int i = 0; i < 2; ++i)
        #pragma unroll
        for (int j = 0; j < 4; ++j) acc[i][j] = (f32x4){0.f, 0.f, 0.f, 0.f};

    for (int k0 = 0; k0 < D_IN; k0 += 32) {
        gload16(abase + (size_t)srow * D_IN + k0 + scol,        u.p1.As + wv * 512);
        gload16(bbase + (size_t)srow * D_IN + k0 + scol,        u.p1.Bs + wv * 512);
        gload16(bbase + (size_t)(64 + srow) * D_IN + k0 + scol, u.p1.Bs + 2048 + wv * 512);
        __syncthreads();   // drains vmcnt incl. async LDS stores
        f16x8 af[2], bf[4];
        #pragma unroll
        for (int ms = 0; ms < 2; ++ms)
            af[ms] = *(const f16x8*)&u.p1.As[(waveM * 32 + ms * 16 + l16) * 32 + quad * 8];
        #pragma unroll
        for (int ns = 0; ns < 4; ++ns)
            bf[ns] = *(const f16x8*)&u.p1.Bs[(waveN * 64 + ns * 16 + l16) * 32 + quad * 8];
        #pragma unroll
        for (int ms = 0; ms < 2; ++ms)
            #pragma unroll
            for (int ns = 0; ns < 4; ++ns)
                acc[ms][ns] = __builtin_amdgcn_mfma_f32_16x16x32_f16(af[ms], bf[ns], acc[ms][ns], 0, 0, 0);
        __syncthreads();
    }

    // h1 = tanh(acc + b1) -> h1s
    #pragma unroll
    for (int ms = 0; ms < 2; ++ms) {
        int rbase = waveM * 32 + ms * 16 + quad * 4;
        #pragma unroll
        for (int ns = 0; ns < 4; ++ns) {
            int n = waveN * 64 + ns * 16 + l16;
            float bias = e1b[e * D_H + n];
            #pragma unroll
            for (int r = 0; r < 4; ++r)
                h1s[(rbase + r) * H1S + n] = (_Float16)tanhf(acc[ms][ns][r] + bias);
        }
    }
    __syncthreads();   // h1s visible; As/Bs dead -> reuse as e2ws

    {
        int rr = t >> 1, cc = (t & 1) * 64;
        const _Float16* src = e2T + (size_t)e * (D_H * D_H) + (size_t)rr * D_H + cc;
        #pragma unroll
        for (int i = 0; i < 8; ++i)
            *(uint4*)&u.e2ws[rr * H1S + cc + i * 8] = *(const uint4*)(src + i * 8);
    }
    __syncthreads();

    f32x4 acc2[2][4];
    #pragma unroll
    for (int i = 0; i < 2; ++i)
        #pragma unroll
        for (int j = 0; j < 4; ++j) acc2[i][j] = (f32x4){0.f, 0.f, 0.f, 0.f};
    #pragma unroll
    for (int kc = 0; kc < 4; ++kc) {
        f16x8 a2[2], b2[4];
        #pragma unroll
        for (int ms = 0; ms < 2; ++ms)
            a2[ms] = *(const f16x8*)&h1s[(waveM * 32 + ms * 16 + l16) * H1S + kc * 32 + quad * 8];
        #pragma unroll
        for (int ns = 0; ns < 4; ++ns)
            b2[ns] = *(const f16x8*)&u.e2ws[(waveN * 64 + ns * 16 + l16) * H1S + kc * 32 + quad * 8];
        #pragma unroll
        for (int ms = 0; ms < 2; ++ms)
            #pragma unroll
            for (int ns = 0; ns < 4; ++ns)
                acc2[ms][ns] = __builtin_amdgcn_mfma_f32_16x16x32_f16(a2[ms], b2[ns], acc2[ms][ns], 0, 0, 0);
    }

    #pragma unroll
    for (int ms = 0; ms < 2; ++ms) {
        int rbase = waveM * 32 + ms * 16 + quad * 4;
        #pragma unroll
        for (int ns = 0; ns < 4; ++ns) {
            int n = waveN * 64 + ns * 16 + l16;
            float bias = e2b[e * D_H + n];
            #pragma unroll
            for (int r = 0; r < 4; ++r) {
                int row = rbase + r;
                float w = wfl[row];
                if (w != 0.f) {
                    float h2 = tanhf(acc2[ms][ns][r] + bias);
                    unsafeAtomicAdd(&moe[(size_t)(m0 + row) * D_H + n], w * h2);
                }
            }
        }
    }
}

// ---------------- kernel 3: head: logits = moe @ smw + smb, softmax -> out
__global__ __launch_bounds__(256) void k_head(
    const float* __restrict__ moe, const float* __restrict__ smw,
    const float* __restrict__ smb, float* __restrict__ out)
{
    __shared__ float moesT[128 * 66];
    __shared__ float smws[1280];
    __shared__ float smbs[16];
    __shared__ float lg[64 * 12];
    int b0 = blockIdx.x * 64;
    int t = threadIdx.x;
    for (int i = t; i < 1280; i += 256) smws[i] = smw[i];
    if (t < 10) smbs[t] = smb[t];
    {
        int row = t >> 2, cb = (t & 3) * 32;
        #pragma unroll
        for (int i = 0; i < 8; ++i) {
            float4 v = *(const float4*)&moe[(size_t)(b0 + row) * D_H + cb + i * 4];
            moesT[(cb + i * 4 + 0) * 66 + row] = v.x;
            moesT[(cb + i * 4 + 1) * 66 + row] = v.y;
            moesT[(cb + i * 4 + 2) * 66 + row] = v.z;
            moesT[(cb + i * 4 + 3) * 66 + row] = v.w;
        }
    }
    __syncthreads();
    {
        int row = t & 63, grp = t >> 6;
        int c0 = grp, c1 = grp + 4, c2 = grp + 8;
        float s0 = 0.f, s1 = 0.f, s2 = 0.f;
        for (int k = 0; k < 128; ++k) {
            float m = moesT[k * 66 + row];
            s0 += m * smws[k * 10 + c0];
            s1 += m * smws[k * 10 + c1];
            if (c2 < 10) s2 += m * smws[k * 10 + c2];
        }
        lg[row * 12 + c0] = s0 + smbs[c0];
        lg[row * 12 + c1] = s1 + smbs[c1];
        if (c2 < 10) lg[row * 12 + c2] = s2 + smbs[c2];
    }
    __syncthreads();
    if (t < 64) {
        float mx = -1e30f;
        for (int c = 0; c < 10; ++c) mx = fmaxf(mx, lg[t * 12 + c]);
        float s = 0.f, ex[10];
        for (int c = 0; c < 10; ++c) { ex[c] = expf(lg[t * 12 + c] - mx); s += ex[c]; }
        float inv = 1.f / s;
        for (int c = 0; c < 10; ++c) out[(size_t)(b0 + t) * 10 + c] = ex[c] * inv;
    }
}

extern "C" void kernel_launch(void* const* d_in, const int* in_sizes, int n_in,
                              void* d_out, int out_size, void* d_ws, size_t ws_size,
                              hipStream_t stream)
{
    const float* x   = (const float*)d_in[0];
    const float* c1w = (const float*)d_in[1];
    const float* c1b = (const float*)d_in[2];
    const float* c2w = (const float*)d_in[3];
    const float* c2b = (const float*)d_in[4];
    const float* gw  = (const float*)d_in[5];
    const float* gb  = (const float*)d_in[6];
    const float* e1w = (const float*)d_in[7];
    const float* e1b = (const float*)d_in[8];
    const float* e2w = (const float*)d_in[9];
    const float* e2b = (const float*)d_in[10];
    const float* smw = (const float*)d_in[11];
    const float* smb = (const float*)d_in[12];
    float* out = (float*)d_out;

    char* ws = (char*)d_ws;
    size_t off = 0;
    auto alloc = [&](size_t bytes) {
        void* p = ws + off;
        off += (bytes + 255) & ~(size_t)255;
        return p;
    };
    _Float16* h16 = (_Float16*)alloc((size_t)NB * D_IN * 2);          // 52.4 MB
    _Float16* wT  = (_Float16*)alloc((size_t)NE * D_H * D_IN * 2);    // 4.1 MB
    _Float16* e2T = (_Float16*)alloc((size_t)NE * D_H * D_H * 2);     // 0.16 MB
    float* wfull  = (float*)alloc((size_t)NB * NE * 4);               // 0.16 MB
    float* moe    = (float*)alloc((size_t)NB * D_H * 4);              // 4.2 MB
    float* gwC    = (float*)alloc((size_t)NE * D_IN * 4);             // 64 KB

    hipMemsetAsync(moe, 0, (size_t)NB * D_H * 4, stream);
    k_wconv<<<dim3(NE, D_IN / 64, D_H / 64), 256, 0, stream>>>(e1w, wT);
    k_wprep2<<<dim3(NE, 2, 2), 256, 0, stream>>>(e2w, e2T);
    k_wgate<<<dim3(63), 256, 0, stream>>>(gw, gwC);
    k_feat<<<dim3(NB), 256, 0, stream>>>(x, c1w, c1b, c2w, c2b, gwC, gb, h16, wfull);
    k_e1e2<<<dim3(NB / 64, NE), 256, 0, stream>>>(h16, wT, e2T, e1b, e2b, wfull, moe);
    k_head<<<dim3(NB / 64), 256, 0, stream>>>(moe, smw, smb, out);
}